// Round 1
// baseline (817.441 us; speedup 1.0000x reference)
//
#include <hip/hip_runtime.h>
#include <cstdint>

// Problem constants
#define BB 2
#define TT 2048
#define DM 2048
#define NH 16
#define HD 128
#define QKVN 6144   // 3*DM

using f32x4   = __attribute__((ext_vector_type(4))) float;
using bf16x8  = __attribute__((ext_vector_type(8))) __bf16;
using ushort8 = __attribute__((ext_vector_type(8))) unsigned short;

static __device__ __forceinline__ unsigned short f2bf(float f) {
    uint32_t u = __builtin_bit_cast(uint32_t, f);
    u += 0x7FFFu + ((u >> 16) & 1u);          // RNE
    return (unsigned short)(u >> 16);
}
static __device__ __forceinline__ float bf2f(unsigned short h) {
    return __builtin_bit_cast(float, ((uint32_t)h) << 16);
}

#define GLOAD16(SRC, DST)                                               \
    __builtin_amdgcn_global_load_lds(                                   \
        (const __attribute__((address_space(1))) void*)(SRC),           \
        (__attribute__((address_space(3))) void*)(DST), 16, 0, 0)

// ---------------------------------------------------------------------------
// 1) elementwise fp32 -> bf16 hi/lo split (for x)
// ---------------------------------------------------------------------------
__global__ __launch_bounds__(256) void k_split(const float* __restrict__ in,
                                               unsigned short* __restrict__ hi,
                                               unsigned short* __restrict__ lo,
                                               int n4) {
    int i = blockIdx.x * 256 + threadIdx.x;
    if (i >= n4) return;
    float4 v = reinterpret_cast<const float4*>(in)[i];
    ushort4 h, l;
    h.x = f2bf(v.x); l.x = f2bf(v.x - bf2f(h.x));
    h.y = f2bf(v.y); l.y = f2bf(v.y - bf2f(h.y));
    h.z = f2bf(v.z); l.z = f2bf(v.z - bf2f(h.z));
    h.w = f2bf(v.w); l.w = f2bf(v.w - bf2f(h.w));
    reinterpret_cast<ushort4*>(hi)[i] = h;
    reinterpret_cast<ushort4*>(lo)[i] = l;
}

// ---------------------------------------------------------------------------
// 2) W [K,N] fp32 -> Wt hi/lo [N,K] bf16  (transpose + split)
// ---------------------------------------------------------------------------
__global__ __launch_bounds__(256) void k_tsplit(const float* __restrict__ W,
                                                unsigned short* __restrict__ th,
                                                unsigned short* __restrict__ tl,
                                                int K, int N) {
    __shared__ float tile[32][33];
    int bn = blockIdx.x * 32, bk = blockIdx.y * 32;
    int tx = threadIdx.x, ty = threadIdx.y;   // 32 x 8
#pragma unroll
    for (int r = 0; r < 4; r++)
        tile[ty + 8 * r][tx] = W[(size_t)(bk + ty + 8 * r) * N + bn + tx];
    __syncthreads();
#pragma unroll
    for (int r = 0; r < 4; r++) {
        float v = tile[tx][ty + 8 * r];
        int row = bn + ty + 8 * r, col = bk + tx;
        unsigned short h = f2bf(v);
        th[(size_t)row * K + col] = h;
        tl[(size_t)row * K + col] = f2bf(v - bf2f(h));
    }
}

// ---------------------------------------------------------------------------
// 3) split-bf16 GEMM:  C[M,N] = (Ah+Al)[M,K] * (Bh+Bl)^T  with Bt[N,K]
//    m97-style: 128x128 tile, BK=32, 4 waves, global_load_lds width 16.
//    EPI 0: write C as bf16 hi/lo.  EPI 1: write fp32 C + bias.
// ---------------------------------------------------------------------------
template <int EPI>
__global__ __launch_bounds__(256) void k_gemm(
    const unsigned short* __restrict__ Ah, const unsigned short* __restrict__ Al,
    const unsigned short* __restrict__ Bh, const unsigned short* __restrict__ Bl,
    unsigned short* __restrict__ Ch, unsigned short* __restrict__ Cl,
    float* __restrict__ Cf, const float* __restrict__ bias,
    int M, int N, int K) {
    __shared__ unsigned short sAh[128 * 32], sAl[128 * 32];
    __shared__ unsigned short sBh[128 * 32], sBl[128 * 32];
    const int tid = threadIdx.x;
    const int wave = tid >> 6, lane = tid & 63;
    const int g = lane >> 4, r16 = lane & 15;
    const int arow0 = blockIdx.y * 128;
    const int bcol0 = blockIdx.x * 128;
    const int wr = (wave >> 1) * 64, wc = (wave & 1) * 64;

    // staging: linear LDS u16 idx = i*2048 + wave*512 + lane*8 -> (row,k)
    const int st_row = (wave << 4) | (lane >> 2);   // + i*64
    const int st_k = (lane & 3) << 3;
    const int lidx = wave * 512 + lane * 8;
    const size_t aoff0 = (size_t)(arow0 + st_row) * K + st_k;
    const size_t boff0 = (size_t)(bcol0 + st_row) * K + st_k;

    f32x4 acc[4][4];
#pragma unroll
    for (int m = 0; m < 4; m++)
#pragma unroll
        for (int n = 0; n < 4; n++) acc[m][n] = (f32x4){0.f, 0.f, 0.f, 0.f};

    for (int kt = 0; kt < K; kt += 32) {
#pragma unroll
        for (int i = 0; i < 2; i++) {
            GLOAD16(Ah + aoff0 + (size_t)(i * 64) * K + kt, &sAh[i * 2048 + lidx]);
            GLOAD16(Al + aoff0 + (size_t)(i * 64) * K + kt, &sAl[i * 2048 + lidx]);
            GLOAD16(Bh + boff0 + (size_t)(i * 64) * K + kt, &sBh[i * 2048 + lidx]);
            GLOAD16(Bl + boff0 + (size_t)(i * 64) * K + kt, &sBl[i * 2048 + lidx]);
        }
        __syncthreads();
        bf16x8 ah[4], al[4], bh[4], bl[4];
#pragma unroll
        for (int m = 0; m < 4; m++) {
            int ro = (wr + m * 16 + r16) * 32 + g * 8;
            ah[m] = __builtin_bit_cast(bf16x8, *(const ushort8*)&sAh[ro]);
            al[m] = __builtin_bit_cast(bf16x8, *(const ushort8*)&sAl[ro]);
        }
#pragma unroll
        for (int n = 0; n < 4; n++) {
            int ro = (wc + n * 16 + r16) * 32 + g * 8;
            bh[n] = __builtin_bit_cast(bf16x8, *(const ushort8*)&sBh[ro]);
            bl[n] = __builtin_bit_cast(bf16x8, *(const ushort8*)&sBl[ro]);
        }
#pragma unroll
        for (int m = 0; m < 4; m++)
#pragma unroll
            for (int n = 0; n < 4; n++) {
                acc[m][n] = __builtin_amdgcn_mfma_f32_16x16x32_bf16(ah[m], bh[n], acc[m][n], 0, 0, 0);
                acc[m][n] = __builtin_amdgcn_mfma_f32_16x16x32_bf16(ah[m], bl[n], acc[m][n], 0, 0, 0);
                acc[m][n] = __builtin_amdgcn_mfma_f32_16x16x32_bf16(al[m], bh[n], acc[m][n], 0, 0, 0);
            }
        __syncthreads();
    }
#pragma unroll
    for (int m = 0; m < 4; m++)
#pragma unroll
        for (int n = 0; n < 4; n++) {
            int col = bcol0 + wc + n * 16 + r16;
#pragma unroll
            for (int j = 0; j < 4; j++) {
                int row = arow0 + wr + m * 16 + g * 4 + j;
                float v = acc[m][n][j];
                if (EPI == 0) {
                    unsigned short h = f2bf(v);
                    Ch[(size_t)row * N + col] = h;
                    Cl[(size_t)row * N + col] = f2bf(v - bf2f(h));
                } else {
                    Cf[(size_t)row * N + col] = v + bias[col];
                }
            }
        }
}

// ---------------------------------------------------------------------------
// 4) RoPE in place on qkv hi/lo (cols 0..4095 = q,k), one block per (b,t) row
// ---------------------------------------------------------------------------
__global__ __launch_bounds__(256) void k_rope(unsigned short* __restrict__ qh,
                                              unsigned short* __restrict__ ql) {
    __shared__ float row[4096];
    __shared__ float cs[64], sn[64];
    const int rb = blockIdx.x;        // b*T + t
    const int t = rb & (TT - 1);
    const int tid = threadIdx.x;
    if (tid < 64) {
        float invf = 1.0f / powf(10000.0f, (float)tid * (1.0f / 64.0f));
        float s, c;
        sincosf((float)t * invf, &s, &c);
        cs[tid] = c; sn[tid] = s;
    }
    const size_t base = (size_t)rb * QKVN;
#pragma unroll
    for (int i = 0; i < 2; i++) {
        int c0 = (tid + i * 256) * 8;
        ushort8 h = *(const ushort8*)&qh[base + c0];
        ushort8 l = *(const ushort8*)&ql[base + c0];
#pragma unroll
        for (int e = 0; e < 8; e++) row[c0 + e] = bf2f(h[e]) + bf2f(l[e]);
    }
    __syncthreads();
#pragma unroll
    for (int i = 0; i < 2; i++) {
        int c0 = (tid + i * 256) * 8;
        int d0 = c0 & 127;
        ushort8 h, l;
#pragma unroll
        for (int e = 0; e < 8; e++) {
            int c = c0 + e, d = d0 + e;
            float x = row[c];
            float xr = (d < 64) ? -row[c + 64] : row[c - 64];
            float v = x * cs[d & 63] + xr * sn[d & 63];
            unsigned short hh = f2bf(v);
            h[e] = hh; l[e] = f2bf(v - bf2f(hh));
        }
        *(ushort8*)&qh[base + c0] = h;
        *(ushort8*)&ql[base + c0] = l;
    }
}

// ---------------------------------------------------------------------------
// 5) extract V^T per head: vt[bh][d][t] = bf16(qkv[b,t, 4096 + h*128 + d])
// ---------------------------------------------------------------------------
__global__ __launch_bounds__(128) void k_vt(const unsigned short* __restrict__ qkvh,
                                            unsigned short* __restrict__ vt) {
    const int bh = blockIdx.x;    // 0..31
    const int tc = blockIdx.y;    // 0..31 (chunk of 64 t's)
    const int d = threadIdx.x;    // 0..127
    const int b = bh >> 4, h = bh & 15;
    unsigned short buf[64];
    const size_t src0 = ((size_t)(b * TT + tc * 64)) * QKVN + 4096 + h * 128 + d;
#pragma unroll
    for (int ttt = 0; ttt < 64; ttt++) buf[ttt] = qkvh[src0 + (size_t)ttt * QKVN];
    const size_t dst = ((size_t)bh * 128 + d) * TT + tc * 64;
#pragma unroll
    for (int i = 0; i < 8; i++)
        *(ushort8*)&vt[dst + i * 8] = *(const ushort8*)&buf[i * 8];
}

// ---------------------------------------------------------------------------
// 6) causal flash attention. grid (T/64, B*H), 4 waves; each wave owns 16 q rows.
//    K tile [32][128] XOR-swizzled (slot ^= row&7); Vt tile [128][32] (slot ^= d&3).
// ---------------------------------------------------------------------------
__global__ __launch_bounds__(256) void k_flash(const unsigned short* __restrict__ qkvh,
                                               const unsigned short* __restrict__ vt,
                                               unsigned short* __restrict__ aoh,
                                               unsigned short* __restrict__ aol) {
    __shared__ unsigned short sK[32 * 128];
    __shared__ unsigned short sV[128 * 32];
    __shared__ unsigned short sP[4][16 * 32];
    const int qb = blockIdx.x, bh = blockIdx.y;
    const int b = bh >> 4, h = bh & 15;
    const int tid = threadIdx.x, wave = tid >> 6, lane = tid & 63;
    const int g = lane >> 4, r16 = lane & 15;
    const float scale = 0.08838834764831845f;   // 1/sqrt(128)

    // Q fragments in registers (A-layout: row=r16, k = kk*32 + g*8 + e)
    const int qrow = qb * 64 + wave * 16 + r16;
    bf16x8 qf[4];
    {
        const size_t qbase = ((size_t)(b * TT) + qrow) * QKVN + h * 128;
#pragma unroll
        for (int kk = 0; kk < 4; kk++)
            qf[kk] = __builtin_bit_cast(bf16x8, *(const ushort8*)&qkvh[qbase + kk * 32 + g * 8]);
    }

    f32x4 oacc[8];
#pragma unroll
    for (int n = 0; n < 8; n++) oacc[n] = (f32x4){0.f, 0.f, 0.f, 0.f};
    float mrun[4], lrun[4];
#pragma unroll
    for (int j = 0; j < 4; j++) { mrun[j] = -1e30f; lrun[j] = 0.f; }

    const int krow_st = (wave << 2) + (lane >> 4);   // + i*16   (K tile row)
    const int kslot = lane & 15;
    const int vrow_st = (wave << 4) + (lane >> 2);   // + i*64   (Vt tile row = d)
    const int vslot = lane & 3;

    const int nkb = 2 * qb + 2;
    for (int kb = 0; kb < nkb; kb++) {
#pragma unroll
        for (int i = 0; i < 2; i++) {
            int krow = i * 16 + krow_st;
            int kgs = kslot ^ (krow & 7);
            GLOAD16(qkvh + ((size_t)(b * TT + kb * 32 + krow)) * QKVN + 2048 + h * 128 + kgs * 8,
                    &sK[i * 2048 + wave * 512 + lane * 8]);
            int vrow = i * 64 + vrow_st;
            int vgs = vslot ^ (vrow & 3);
            GLOAD16(vt + ((size_t)bh * 128 + vrow) * TT + kb * 32 + vgs * 8,
                    &sV[i * 2048 + wave * 512 + lane * 8]);
        }
        __syncthreads();

        // S = Q K^T  (two 16-key fragments)
        f32x4 sacc[2];
        sacc[0] = (f32x4){0.f, 0.f, 0.f, 0.f};
        sacc[1] = (f32x4){0.f, 0.f, 0.f, 0.f};
#pragma unroll
        for (int n = 0; n < 2; n++) {
            int krow = n * 16 + r16;
#pragma unroll
            for (int kk = 0; kk < 4; kk++) {
                int slot = (kk * 4 + g) ^ (krow & 7);
                bf16x8 kf = __builtin_bit_cast(bf16x8, *(const ushort8*)&sK[krow * 128 + slot * 8]);
                sacc[n] = __builtin_amdgcn_mfma_f32_16x16x32_bf16(qf[kk], kf, sacc[n], 0, 0, 0);
            }
        }

        // online softmax (per wave, rows q = wave*16 + g*4 + j)
        const int key0 = kb * 32;
#pragma unroll
        for (int j = 0; j < 4; j++) {
            int qg = qb * 64 + wave * 16 + g * 4 + j;
            float s0 = sacc[0][j] * scale, s1 = sacc[1][j] * scale;
            if (key0 + r16 > qg) s0 = -1e30f;
            if (key0 + 16 + r16 > qg) s1 = -1e30f;
            float tmax = fmaxf(s0, s1);
#pragma unroll
            for (int off = 8; off >= 1; off >>= 1) tmax = fmaxf(tmax, __shfl_xor(tmax, off));
            float mnew = fmaxf(mrun[j], tmax);
            float corr = __expf(mrun[j] - mnew);
            float p0 = __expf(s0 - mnew), p1 = __expf(s1 - mnew);
            float rs = p0 + p1;
#pragma unroll
            for (int off = 8; off >= 1; off >>= 1) rs += __shfl_xor(rs, off);
            lrun[j] = lrun[j] * corr + rs;
            mrun[j] = mnew;
#pragma unroll
            for (int n = 0; n < 8; n++) oacc[n][j] *= corr;
            int prow = g * 4 + j;
            int k0 = r16, k1 = 16 + r16;
            sP[wave][prow * 32 + (((k0 >> 3) ^ (prow & 3)) << 3) + (k0 & 7)] = f2bf(p0);
            sP[wave][prow * 32 + (((k1 >> 3) ^ (prow & 3)) << 3) + (k1 & 7)] = f2bf(p1);
        }

        // PV
        {
            int prow = r16;
            bf16x8 pf = __builtin_bit_cast(bf16x8,
                *(const ushort8*)&sP[wave][prow * 32 + ((g ^ (prow & 3)) << 3)]);
#pragma unroll
            for (int n = 0; n < 8; n++) {
                int vrow = n * 16 + r16;                 // d row of Vt
                int slot = g ^ (vrow & 3);
                bf16x8 vf = __builtin_bit_cast(bf16x8, *(const ushort8*)&sV[vrow * 32 + slot * 8]);
                oacc[n] = __builtin_amdgcn_mfma_f32_16x16x32_bf16(pf, vf, oacc[n], 0, 0, 0);
            }
        }
        __syncthreads();
    }

#pragma unroll
    for (int j = 0; j < 4; j++) {
        float inv = 1.0f / lrun[j];
        int qg = qb * 64 + wave * 16 + g * 4 + j;
        size_t obase = ((size_t)(b * TT) + qg) * DM + h * 128;
#pragma unroll
        for (int n = 0; n < 8; n++) {
            float v = oacc[n][j] * inv;
            unsigned short hh = f2bf(v);
            aoh[obase + n * 16 + r16] = hh;
            aol[obase + n * 16 + r16] = f2bf(v - bf2f(hh));
        }
    }
}

// ---------------------------------------------------------------------------
extern "C" void kernel_launch(void* const* d_in, const int* in_sizes, int n_in,
                              void* d_out, int out_size, void* d_ws, size_t ws_size,
                              hipStream_t stream) {
    const float* x = (const float*)d_in[0];
    const float* Wqkv = (const float*)d_in[1];
    const float* Wproj = (const float*)d_in[2];
    const float* bproj = (const float*)d_in[3];
    // d_in[4] = mask (causal structure implemented directly)

    uint8_t* w = (uint8_t*)d_ws;
    auto alloc = [&](size_t bytes) { uint8_t* p = w; w += bytes; return p; };
    unsigned short* xh   = (unsigned short*)alloc(8388608ull * 2);   // x hi
    unsigned short* xl   = (unsigned short*)alloc(8388608ull * 2);   // x lo
    unsigned short* wqh  = (unsigned short*)alloc(12582912ull * 2);  // WqkvT hi [6144][2048]
    unsigned short* wql  = (unsigned short*)alloc(12582912ull * 2);
    unsigned short* wph  = (unsigned short*)alloc(4194304ull * 2);   // WprojT hi [2048][2048]
    unsigned short* wpl  = (unsigned short*)alloc(4194304ull * 2);
    unsigned short* qkvh = (unsigned short*)alloc(25165824ull * 2);  // qkv hi [4096][6144]
    unsigned short* qkvl = (unsigned short*)alloc(25165824ull * 2);
    unsigned short* vtp  = (unsigned short*)alloc(8388608ull * 2);   // V^T [32][128][2048]
    unsigned short* aoh  = (unsigned short*)alloc(8388608ull * 2);   // attn out hi [4096][2048]
    unsigned short* aol  = (unsigned short*)alloc(8388608ull * 2);

    k_split<<<dim3(8192), dim3(256), 0, stream>>>(x, xh, xl, 2097152);
    k_tsplit<<<dim3(192, 64), dim3(32, 8), 0, stream>>>(Wqkv, wqh, wql, 2048, 6144);
    k_tsplit<<<dim3(64, 64), dim3(32, 8), 0, stream>>>(Wproj, wph, wpl, 2048, 2048);
    k_gemm<0><<<dim3(48, 32), dim3(256), 0, stream>>>(xh, xl, wqh, wql,
                                                      qkvh, qkvl, nullptr, nullptr,
                                                      4096, 6144, 2048);
    k_rope<<<dim3(4096), dim3(256), 0, stream>>>(qkvh, qkvl);
    k_vt<<<dim3(32, 32), dim3(128), 0, stream>>>(qkvh, vtp);
    k_flash<<<dim3(32, 32), dim3(256), 0, stream>>>(qkvh, vtp, aoh, aol);
    k_gemm<1><<<dim3(16, 32), dim3(256), 0, stream>>>(aoh, aol, wph, wpl,
                                                      nullptr, nullptr,
                                                      (float*)d_out, bproj,
                                                      4096, 2048, 2048);
}

// Round 2
// 733.719 us; speedup vs baseline: 1.1141x; 1.1141x over previous
//
#include <hip/hip_runtime.h>
#include <cstdint>

// Problem constants
#define BB 2
#define TT 2048
#define DM 2048
#define NH 16
#define HD 128
#define QKVN 6144   // 3*DM

using f32x4   = __attribute__((ext_vector_type(4))) float;
using bf16x8  = __attribute__((ext_vector_type(8))) __bf16;
using ushort8 = __attribute__((ext_vector_type(8))) unsigned short;

static __device__ __forceinline__ unsigned short f2bf(float f) {
    uint32_t u = __builtin_bit_cast(uint32_t, f);
    u += 0x7FFFu + ((u >> 16) & 1u);          // RNE
    return (unsigned short)(u >> 16);
}
static __device__ __forceinline__ float bf2f(unsigned short h) {
    return __builtin_bit_cast(float, ((uint32_t)h) << 16);
}

#define GLOAD16(SRC, DST)                                               \
    __builtin_amdgcn_global_load_lds(                                   \
        (const __attribute__((address_space(1))) void*)(SRC),           \
        (__attribute__((address_space(3))) void*)(DST), 16, 0, 0)

// ---------------------------------------------------------------------------
// 1) elementwise fp32 -> bf16 hi/lo split (for x)
// ---------------------------------------------------------------------------
__global__ __launch_bounds__(256) void k_split(const float* __restrict__ in,
                                               unsigned short* __restrict__ hi,
                                               unsigned short* __restrict__ lo,
                                               int n4) {
    int i = blockIdx.x * 256 + threadIdx.x;
    if (i >= n4) return;
    float4 v = reinterpret_cast<const float4*>(in)[i];
    ushort4 h, l;
    h.x = f2bf(v.x); l.x = f2bf(v.x - bf2f(h.x));
    h.y = f2bf(v.y); l.y = f2bf(v.y - bf2f(h.y));
    h.z = f2bf(v.z); l.z = f2bf(v.z - bf2f(h.z));
    h.w = f2bf(v.w); l.w = f2bf(v.w - bf2f(h.w));
    reinterpret_cast<ushort4*>(hi)[i] = h;
    reinterpret_cast<ushort4*>(lo)[i] = l;
}

// ---------------------------------------------------------------------------
// 2) W [K,N] fp32 -> Wt hi/lo [N,K] bf16  (transpose + split)
// ---------------------------------------------------------------------------
__global__ __launch_bounds__(256) void k_tsplit(const float* __restrict__ W,
                                                unsigned short* __restrict__ th,
                                                unsigned short* __restrict__ tl,
                                                int K, int N) {
    __shared__ float tile[32][33];
    int bn = blockIdx.x * 32, bk = blockIdx.y * 32;
    int tx = threadIdx.x, ty = threadIdx.y;   // 32 x 8
#pragma unroll
    for (int r = 0; r < 4; r++)
        tile[ty + 8 * r][tx] = W[(size_t)(bk + ty + 8 * r) * N + bn + tx];
    __syncthreads();
#pragma unroll
    for (int r = 0; r < 4; r++) {
        float v = tile[tx][ty + 8 * r];
        int row = bn + ty + 8 * r, col = bk + tx;
        unsigned short h = f2bf(v);
        th[(size_t)row * K + col] = h;
        tl[(size_t)row * K + col] = f2bf(v - bf2f(h));
    }
}

// ---------------------------------------------------------------------------
// 3) split-bf16 GEMM:  C[M,N] = (Ah+Al)[M,K] * (Bh+Bl)^T  with Bt[N,K]
//    m97-style: 128x128 tile, BK=32, 4 waves, global_load_lds width 16.
//    EPI 0: write C as bf16 hi/lo.  EPI 1: write fp32 C + bias.
// ---------------------------------------------------------------------------
template <int EPI>
__global__ __launch_bounds__(256) void k_gemm(
    const unsigned short* __restrict__ Ah, const unsigned short* __restrict__ Al,
    const unsigned short* __restrict__ Bh, const unsigned short* __restrict__ Bl,
    unsigned short* __restrict__ Ch, unsigned short* __restrict__ Cl,
    float* __restrict__ Cf, const float* __restrict__ bias,
    int M, int N, int K) {
    __shared__ unsigned short sAh[128 * 32], sAl[128 * 32];
    __shared__ unsigned short sBh[128 * 32], sBl[128 * 32];
    const int tid = threadIdx.x;
    const int wave = tid >> 6, lane = tid & 63;
    const int g = lane >> 4, r16 = lane & 15;
    const int arow0 = blockIdx.y * 128;
    const int bcol0 = blockIdx.x * 128;
    const int wr = (wave >> 1) * 64, wc = (wave & 1) * 64;

    // staging: linear LDS u16 idx = i*2048 + wave*512 + lane*8 -> (row,k)
    const int st_row = (wave << 4) | (lane >> 2);   // + i*64
    const int st_k = (lane & 3) << 3;
    const int lidx = wave * 512 + lane * 8;
    const size_t aoff0 = (size_t)(arow0 + st_row) * K + st_k;
    const size_t boff0 = (size_t)(bcol0 + st_row) * K + st_k;

    f32x4 acc[4][4];
#pragma unroll
    for (int m = 0; m < 4; m++)
#pragma unroll
        for (int n = 0; n < 4; n++) acc[m][n] = (f32x4){0.f, 0.f, 0.f, 0.f};

    for (int kt = 0; kt < K; kt += 32) {
#pragma unroll
        for (int i = 0; i < 2; i++) {
            GLOAD16(Ah + aoff0 + (size_t)(i * 64) * K + kt, &sAh[i * 2048 + lidx]);
            GLOAD16(Al + aoff0 + (size_t)(i * 64) * K + kt, &sAl[i * 2048 + lidx]);
            GLOAD16(Bh + boff0 + (size_t)(i * 64) * K + kt, &sBh[i * 2048 + lidx]);
            GLOAD16(Bl + boff0 + (size_t)(i * 64) * K + kt, &sBl[i * 2048 + lidx]);
        }
        __syncthreads();
        bf16x8 ah[4], al[4], bh[4], bl[4];
#pragma unroll
        for (int m = 0; m < 4; m++) {
            int ro = (wr + m * 16 + r16) * 32 + g * 8;
            ah[m] = __builtin_bit_cast(bf16x8, *(const ushort8*)&sAh[ro]);
            al[m] = __builtin_bit_cast(bf16x8, *(const ushort8*)&sAl[ro]);
        }
#pragma unroll
        for (int n = 0; n < 4; n++) {
            int ro = (wc + n * 16 + r16) * 32 + g * 8;
            bh[n] = __builtin_bit_cast(bf16x8, *(const ushort8*)&sBh[ro]);
            bl[n] = __builtin_bit_cast(bf16x8, *(const ushort8*)&sBl[ro]);
        }
#pragma unroll
        for (int m = 0; m < 4; m++)
#pragma unroll
            for (int n = 0; n < 4; n++) {
                acc[m][n] = __builtin_amdgcn_mfma_f32_16x16x32_bf16(ah[m], bh[n], acc[m][n], 0, 0, 0);
                acc[m][n] = __builtin_amdgcn_mfma_f32_16x16x32_bf16(ah[m], bl[n], acc[m][n], 0, 0, 0);
                acc[m][n] = __builtin_amdgcn_mfma_f32_16x16x32_bf16(al[m], bh[n], acc[m][n], 0, 0, 0);
            }
        __syncthreads();
    }
#pragma unroll
    for (int m = 0; m < 4; m++)
#pragma unroll
        for (int n = 0; n < 4; n++) {
            int col = bcol0 + wc + n * 16 + r16;
#pragma unroll
            for (int j = 0; j < 4; j++) {
                int row = arow0 + wr + m * 16 + g * 4 + j;
                float v = acc[m][n][j];
                if (EPI == 0) {
                    unsigned short h = f2bf(v);
                    Ch[(size_t)row * N + col] = h;
                    Cl[(size_t)row * N + col] = f2bf(v - bf2f(h));
                } else {
                    Cf[(size_t)row * N + col] = v + bias[col];
                }
            }
        }
}

// ---------------------------------------------------------------------------
// 4) RoPE in place on qkv hi/lo (cols 0..4095 = q,k), one block per (b,t) row
// ---------------------------------------------------------------------------
__global__ __launch_bounds__(256) void k_rope(unsigned short* __restrict__ qh,
                                              unsigned short* __restrict__ ql) {
    __shared__ float row[4096];
    __shared__ float cs[64], sn[64];
    const int rb = blockIdx.x;        // b*T + t
    const int t = rb & (TT - 1);
    const int tid = threadIdx.x;
    if (tid < 64) {
        float invf = 1.0f / powf(10000.0f, (float)tid * (1.0f / 64.0f));
        float s, c;
        sincosf((float)t * invf, &s, &c);
        cs[tid] = c; sn[tid] = s;
    }
    const size_t base = (size_t)rb * QKVN;
#pragma unroll
    for (int i = 0; i < 2; i++) {
        int c0 = (tid + i * 256) * 8;
        ushort8 h = *(const ushort8*)&qh[base + c0];
        ushort8 l = *(const ushort8*)&ql[base + c0];
#pragma unroll
        for (int e = 0; e < 8; e++) row[c0 + e] = bf2f(h[e]) + bf2f(l[e]);
    }
    __syncthreads();
#pragma unroll
    for (int i = 0; i < 2; i++) {
        int c0 = (tid + i * 256) * 8;
        int d0 = c0 & 127;
        ushort8 h, l;
#pragma unroll
        for (int e = 0; e < 8; e++) {
            int c = c0 + e, d = d0 + e;
            float x = row[c];
            float xr = (d < 64) ? -row[c + 64] : row[c - 64];
            float v = x * cs[d & 63] + xr * sn[d & 63];
            unsigned short hh = f2bf(v);
            h[e] = hh; l[e] = f2bf(v - bf2f(hh));
        }
        *(ushort8*)&qh[base + c0] = h;
        *(ushort8*)&ql[base + c0] = l;
    }
}

// ---------------------------------------------------------------------------
// 5) extract V^T per head: vt[bh][d][t] = bf16(qkv[b,t, 4096 + h*128 + d])
// ---------------------------------------------------------------------------
__global__ __launch_bounds__(128) void k_vt(const unsigned short* __restrict__ qkvh,
                                            unsigned short* __restrict__ vt) {
    const int bh = blockIdx.x;    // 0..31
    const int tc = blockIdx.y;    // 0..31 (chunk of 64 t's)
    const int d = threadIdx.x;    // 0..127
    const int b = bh >> 4, h = bh & 15;
    unsigned short buf[64];
    const size_t src0 = ((size_t)(b * TT + tc * 64)) * QKVN + 4096 + h * 128 + d;
#pragma unroll
    for (int ttt = 0; ttt < 64; ttt++) buf[ttt] = qkvh[src0 + (size_t)ttt * QKVN];
    const size_t dst = ((size_t)bh * 128 + d) * TT + tc * 64;
#pragma unroll
    for (int i = 0; i < 8; i++)
        *(ushort8*)&vt[dst + i * 8] = *(const ushort8*)&buf[i * 8];
}

// ---------------------------------------------------------------------------
// 6) causal flash attention v2.
//    QBLK=64 (4 waves x 16 q rows), KVBLK=64, double-buffered K/V staging
//    (T3-minimum: stage(t+1) after the single per-tile barrier), XCD-aware
//    block remap (4 heads' K/V = 4MB = one XCD L2), heavy qb first.
//    sK [64][128] slot^=row&7; sV=[Vt 128][64] slot^=row&7; sP [16][64] same.
// ---------------------------------------------------------------------------
__global__ __launch_bounds__(256) void k_flash(const unsigned short* __restrict__ qkvh,
                                               const unsigned short* __restrict__ vt,
                                               unsigned short* __restrict__ aoh,
                                               unsigned short* __restrict__ aol) {
    __shared__ unsigned short sK[2][64 * 128];
    __shared__ unsigned short sV[2][128 * 64];
    __shared__ unsigned short sP[4][16 * 64];

    // XCD remap: launched id L (x fastest) -> XCD c=L%8 handles logical ids
    // c*128..c*128+127 = heads 4c..4c+3 entirely; qb descending (heavy first).
    const int L = blockIdx.y * gridDim.x + blockIdx.x;
    const int logical = (L & 7) * 128 + (L >> 3);
    const int bh = logical >> 5;
    const int qb = 31 - (logical & 31);
    const int b = bh >> 4, h = bh & 15;

    const int tid = threadIdx.x, wave = tid >> 6, lane = tid & 63;
    const int g = lane >> 4, r16 = lane & 15;
    const float scale = 0.08838834764831845f;   // 1/sqrt(128)

    // Q fragments, pre-scaled by 1/sqrt(hd). A-layout: row=r16, k=kk*32+g*8+e
    bf16x8 qf[4];
    {
        const int qrow = qb * 64 + wave * 16 + r16;
        const size_t qbase = ((size_t)(b * TT) + qrow) * QKVN + h * 128;
#pragma unroll
        for (int kk = 0; kk < 4; kk++) {
            ushort8 u = *(const ushort8*)&qkvh[qbase + kk * 32 + g * 8];
            ushort8 o;
#pragma unroll
            for (int e = 0; e < 8; e++) o[e] = f2bf(bf2f(u[e]) * scale);
            qf[kk] = __builtin_bit_cast(bf16x8, o);
        }
    }

    f32x4 oacc[8];
#pragma unroll
    for (int n = 0; n < 8; n++) oacc[n] = (f32x4){0.f, 0.f, 0.f, 0.f};
    float mrun[4], lrun[4];
#pragma unroll
    for (int j = 0; j < 4; j++) { mrun[j] = -1e30f; lrun[j] = 0.f; }

    // staging geometry (per i-round): dest u16 idx = i*2048 + wave*512 + lane*8
    const int k_row_st = wave * 4 + (lane >> 4);    // + i*16 ; slot = lane&15
    const int v_row_st = wave * 8 + (lane >> 3);    // + i*32 ; slot = lane&7
    const int lidx = wave * 512 + lane * 8;

    auto stage = [&](int buf, int kb) {
#pragma unroll
        for (int i = 0; i < 4; i++) {
            int krow = i * 16 + k_row_st;
            int kcol = ((lane & 15) ^ (krow & 7)) << 3;
            GLOAD16(qkvh + ((size_t)(b * TT + kb * 64 + krow)) * QKVN + 2048 + h * 128 + kcol,
                    &sK[buf][i * 2048 + lidx]);
            int vrow = i * 32 + v_row_st;
            int vcol = ((lane & 7) ^ (vrow & 7)) << 3;
            GLOAD16(vt + ((size_t)bh * 128 + vrow) * TT + kb * 64 + vcol,
                    &sV[buf][i * 2048 + lidx]);
        }
    };

    const int nkb = qb + 1;
    int cur = 0;
    stage(0, 0);

    for (int kb = 0; kb < nkb; kb++) {
        __syncthreads();                      // drains vmcnt: buf[cur] ready
        if (kb + 1 < nkb) stage(cur ^ 1, kb + 1);   // in flight during compute

        // S = Q K^T : 4 key fragments of 16
        f32x4 sacc[4];
#pragma unroll
        for (int n = 0; n < 4; n++) sacc[n] = (f32x4){0.f, 0.f, 0.f, 0.f};
#pragma unroll
        for (int n = 0; n < 4; n++) {
            const int krow = n * 16 + r16;
            const int rbase = krow * 128;
            const int sw = krow & 7;
#pragma unroll
            for (int kk = 0; kk < 4; kk++) {
                int slot = (kk * 4 + g) ^ sw;
                bf16x8 kf = __builtin_bit_cast(bf16x8, *(const ushort8*)&sK[cur][rbase + slot * 8]);
                sacc[n] = __builtin_amdgcn_mfma_f32_16x16x32_bf16(qf[kk], kf, sacc[n], 0, 0, 0);
            }
        }

        // online softmax; rows q = wave*16 + g*4 + j
        const int key0 = kb * 64;
#pragma unroll
        for (int j = 0; j < 4; j++) {
            const int prow = g * 4 + j;
            const int qg = qb * 64 + wave * 16 + prow;
            float s0 = sacc[0][j], s1 = sacc[1][j], s2 = sacc[2][j], s3 = sacc[3][j];
            if (kb == qb) {                     // diagonal tile: causal mask
                if (key0 + r16 > qg)      s0 = -1e30f;
                if (key0 + 16 + r16 > qg) s1 = -1e30f;
                if (key0 + 32 + r16 > qg) s2 = -1e30f;
                if (key0 + 48 + r16 > qg) s3 = -1e30f;
            }
            float tmax = fmaxf(fmaxf(s0, s1), fmaxf(s2, s3));
#pragma unroll
            for (int off = 8; off >= 1; off >>= 1) tmax = fmaxf(tmax, __shfl_xor(tmax, off));
            float mnew = fmaxf(mrun[j], tmax);
            float corr = __expf(mrun[j] - mnew);
            float p0 = __expf(s0 - mnew), p1 = __expf(s1 - mnew);
            float p2 = __expf(s2 - mnew), p3 = __expf(s3 - mnew);
            float rs = (p0 + p1) + (p2 + p3);
#pragma unroll
            for (int off = 8; off >= 1; off >>= 1) rs += __shfl_xor(rs, off);
            lrun[j] = lrun[j] * corr + rs;
            mrun[j] = mnew;
#pragma unroll
            for (int n = 0; n < 8; n++) oacc[n][j] *= corr;
            const int pb = prow * 64, sw = prow & 7, e = r16 & 7, hi2 = (r16 >> 3);
            sP[wave][pb + (((0 + hi2) ^ sw) << 3) + e] = f2bf(p0);
            sP[wave][pb + (((2 + hi2) ^ sw) << 3) + e] = f2bf(p1);
            sP[wave][pb + (((4 + hi2) ^ sw) << 3) + e] = f2bf(p2);
            sP[wave][pb + (((6 + hi2) ^ sw) << 3) + e] = f2bf(p3);
        }

        // PV: oacc[n] += P[16q x 64k] * Vt[d=n*16+r16][k]
#pragma unroll
        for (int kk = 0; kk < 2; kk++) {
            const int slot = (kk * 4 + g) ^ (r16 & 7);
            bf16x8 pf = __builtin_bit_cast(bf16x8, *(const ushort8*)&sP[wave][r16 * 64 + slot * 8]);
#pragma unroll
            for (int n = 0; n < 8; n++) {
                const int d = n * 16 + r16;
                bf16x8 vf = __builtin_bit_cast(bf16x8, *(const ushort8*)&sV[cur][d * 64 + slot * 8]);
                oacc[n] = __builtin_amdgcn_mfma_f32_16x16x32_bf16(pf, vf, oacc[n], 0, 0, 0);
            }
        }
        cur ^= 1;
    }

#pragma unroll
    for (int j = 0; j < 4; j++) {
        float inv = 1.0f / lrun[j];
        int qg = qb * 64 + wave * 16 + g * 4 + j;
        size_t obase = ((size_t)(b * TT) + qg) * DM + h * 128;
#pragma unroll
        for (int n = 0; n < 8; n++) {
            float v = oacc[n][j] * inv;
            unsigned short hh = f2bf(v);
            aoh[obase + n * 16 + r16] = hh;
            aol[obase + n * 16 + r16] = f2bf(v - bf2f(hh));
        }
    }
}

// ---------------------------------------------------------------------------
extern "C" void kernel_launch(void* const* d_in, const int* in_sizes, int n_in,
                              void* d_out, int out_size, void* d_ws, size_t ws_size,
                              hipStream_t stream) {
    const float* x = (const float*)d_in[0];
    const float* Wqkv = (const float*)d_in[1];
    const float* Wproj = (const float*)d_in[2];
    const float* bproj = (const float*)d_in[3];
    // d_in[4] = mask (causal structure implemented directly)

    uint8_t* w = (uint8_t*)d_ws;
    auto alloc = [&](size_t bytes) { uint8_t* p = w; w += bytes; return p; };
    unsigned short* xh   = (unsigned short*)alloc(8388608ull * 2);   // x hi
    unsigned short* xl   = (unsigned short*)alloc(8388608ull * 2);   // x lo
    unsigned short* wqh  = (unsigned short*)alloc(12582912ull * 2);  // WqkvT hi [6144][2048]
    unsigned short* wql  = (unsigned short*)alloc(12582912ull * 2);
    unsigned short* wph  = (unsigned short*)alloc(4194304ull * 2);   // WprojT hi [2048][2048]
    unsigned short* wpl  = (unsigned short*)alloc(4194304ull * 2);
    unsigned short* qkvh = (unsigned short*)alloc(25165824ull * 2);  // qkv hi [4096][6144]
    unsigned short* qkvl = (unsigned short*)alloc(25165824ull * 2);
    unsigned short* vtp  = (unsigned short*)alloc(8388608ull * 2);   // V^T [32][128][2048]
    unsigned short* aoh  = (unsigned short*)alloc(8388608ull * 2);   // attn out hi [4096][2048]
    unsigned short* aol  = (unsigned short*)alloc(8388608ull * 2);

    k_split<<<dim3(8192), dim3(256), 0, stream>>>(x, xh, xl, 2097152);
    k_tsplit<<<dim3(192, 64), dim3(32, 8), 0, stream>>>(Wqkv, wqh, wql, 2048, 6144);
    k_tsplit<<<dim3(64, 64), dim3(32, 8), 0, stream>>>(Wproj, wph, wpl, 2048, 2048);
    k_gemm<0><<<dim3(48, 32), dim3(256), 0, stream>>>(xh, xl, wqh, wql,
                                                      qkvh, qkvl, nullptr, nullptr,
                                                      4096, 6144, 2048);
    k_rope<<<dim3(4096), dim3(256), 0, stream>>>(qkvh, qkvl);
    k_vt<<<dim3(32, 32), dim3(128), 0, stream>>>(qkvh, vtp);
    k_flash<<<dim3(32, 32), dim3(256), 0, stream>>>(qkvh, vtp, aoh, aol);
    k_gemm<1><<<dim3(16, 32), dim3(256), 0, stream>>>(aoh, aol, wph, wpl,
                                                      nullptr, nullptr,
                                                      (float*)d_out, bproj,
                                                      4096, 2048, 2048);
}

// Round 3
// 714.000 us; speedup vs baseline: 1.1449x; 1.0276x over previous
//
#include <hip/hip_runtime.h>
#include <cstdint>

// Problem constants
#define BB 2
#define TT 2048
#define DM 2048
#define NH 16
#define HD 128
#define QKVN 6144   // 3*DM

using f32x4   = __attribute__((ext_vector_type(4))) float;
using bf16x8  = __attribute__((ext_vector_type(8))) __bf16;
using ushort8 = __attribute__((ext_vector_type(8))) unsigned short;

static __device__ __forceinline__ unsigned short f2bf(float f) {
    uint32_t u = __builtin_bit_cast(uint32_t, f);
    u += 0x7FFFu + ((u >> 16) & 1u);          // RNE
    return (unsigned short)(u >> 16);
}
static __device__ __forceinline__ float bf2f(unsigned short h) {
    return __builtin_bit_cast(float, ((uint32_t)h) << 16);
}

#define GLOAD16(SRC, DST)                                               \
    __builtin_amdgcn_global_load_lds(                                   \
        (const __attribute__((address_space(1))) void*)(SRC),           \
        (__attribute__((address_space(3))) void*)(DST), 16, 0, 0)

// ---------------------------------------------------------------------------
// 1) elementwise fp32 -> bf16 hi/lo split (for x)
// ---------------------------------------------------------------------------
__global__ __launch_bounds__(256) void k_split(const float* __restrict__ in,
                                               unsigned short* __restrict__ hi,
                                               unsigned short* __restrict__ lo,
                                               int n4) {
    int i = blockIdx.x * 256 + threadIdx.x;
    if (i >= n4) return;
    float4 v = reinterpret_cast<const float4*>(in)[i];
    ushort4 h, l;
    h.x = f2bf(v.x); l.x = f2bf(v.x - bf2f(h.x));
    h.y = f2bf(v.y); l.y = f2bf(v.y - bf2f(h.y));
    h.z = f2bf(v.z); l.z = f2bf(v.z - bf2f(h.z));
    h.w = f2bf(v.w); l.w = f2bf(v.w - bf2f(h.w));
    reinterpret_cast<ushort4*>(hi)[i] = h;
    reinterpret_cast<ushort4*>(lo)[i] = l;
}

// ---------------------------------------------------------------------------
// 2) W [K,N] fp32 -> Wt hi/lo [N,K] bf16  (transpose + split)
// ---------------------------------------------------------------------------
__global__ __launch_bounds__(256) void k_tsplit(const float* __restrict__ W,
                                                unsigned short* __restrict__ th,
                                                unsigned short* __restrict__ tl,
                                                int K, int N) {
    __shared__ float tile[32][33];
    int bn = blockIdx.x * 32, bk = blockIdx.y * 32;
    int tx = threadIdx.x, ty = threadIdx.y;   // 32 x 8
#pragma unroll
    for (int r = 0; r < 4; r++)
        tile[ty + 8 * r][tx] = W[(size_t)(bk + ty + 8 * r) * N + bn + tx];
    __syncthreads();
#pragma unroll
    for (int r = 0; r < 4; r++) {
        float v = tile[tx][ty + 8 * r];
        int row = bn + ty + 8 * r, col = bk + tx;
        unsigned short h = f2bf(v);
        th[(size_t)row * K + col] = h;
        tl[(size_t)row * K + col] = f2bf(v - bf2f(h));
    }
}

// ---------------------------------------------------------------------------
// 3) split-bf16 GEMM, pipelined (T3+T4+T5+T1):
//    BM=256, BN=128, BK=32, 8 waves (4m x 2n), 64x64 per wave, 4x4 acc.
//    Triple-buffered LDS ring (144 KB), 2-deep prefetch, ONE barrier/K-tile,
//    counted s_waitcnt vmcnt(6) (never drains mid-loop), 4 phases/K-tile with
//    lgkmcnt(0)+sched_barrier+setprio(1) around each 12-MFMA cluster.
//    EPI 0: write C as bf16 hi/lo.  EPI 1: write fp32 C + bias.
// ---------------------------------------------------------------------------
template <int EPI>
__global__ __launch_bounds__(512, 2) void k_gemm(
    const unsigned short* __restrict__ Ah, const unsigned short* __restrict__ Al,
    const unsigned short* __restrict__ Bh, const unsigned short* __restrict__ Bl,
    unsigned short* __restrict__ Ch, unsigned short* __restrict__ Cl,
    float* __restrict__ Cf, const float* __restrict__ bias,
    int M, int N, int K) {
    __shared__ unsigned short sAh[3][8192];   // 256 x 32
    __shared__ unsigned short sAl[3][8192];
    __shared__ unsigned short sBh[3][4096];   // 128 x 32
    __shared__ unsigned short sBl[3][4096];

    // T1: bijective XCD swizzle (nwg % 8 == 0 for both call sites).
    const int nwg = gridDim.x * gridDim.y;
    const int L = blockIdx.y * gridDim.x + blockIdx.x;
    const int logical = (L & 7) * (nwg >> 3) + (L >> 3);
    const int bx = logical % gridDim.x, by = logical / gridDim.x;

    const int tid = threadIdx.x;
    const int wave = tid >> 6, lane = tid & 63;
    const int g = lane >> 4, r16 = lane & 15;
    const int arow0 = by * 256;
    const int bcol0 = bx * 128;
    const int wr = (wave >> 1) * 64, wc = (wave & 1) * 64;

    // staging addresses: thread t covers (row = t/4, kslot = t%4) of a 128-row round
    const int srow = tid >> 2;
    const int skc = (tid & 3) << 3;
    const size_t aoff = (size_t)(arow0 + srow) * K + skc;          // + i*128*K
    const size_t boff = (size_t)(bcol0 + srow) * K + skc;
    const int lidx = tid * 8;                                       // u16 units

    f32x4 acc[4][4];
#pragma unroll
    for (int m = 0; m < 4; m++)
#pragma unroll
        for (int n = 0; n < 4; n++) acc[m][n] = (f32x4){0.f, 0.f, 0.f, 0.f};

    const int NT = K >> 5;

    // stage pair p (p=0: Ah both rounds, p=1: Al both rounds, p=2: Bh+Bl)
    auto stage_pair = [&](int buf, int tk, int p) {
        const size_t kof = (size_t)tk * 32;
        if (p == 0) {
            GLOAD16(Ah + aoff + kof,                    &sAh[buf][lidx]);
            GLOAD16(Ah + aoff + (size_t)128 * K + kof,  &sAh[buf][4096 + lidx]);
        } else if (p == 1) {
            GLOAD16(Al + aoff + kof,                    &sAl[buf][lidx]);
            GLOAD16(Al + aoff + (size_t)128 * K + kof,  &sAl[buf][4096 + lidx]);
        } else {
            GLOAD16(Bh + boff + kof,                    &sBh[buf][lidx]);
            GLOAD16(Bl + boff + kof,                    &sBl[buf][lidx]);
        }
    };

    // prologue: 2-deep prefetch (12 loads outstanding per thread)
    stage_pair(0, 0, 0); stage_pair(0, 0, 1); stage_pair(0, 0, 2);
    if (NT > 1) { stage_pair(1, 1, 0); stage_pair(1, 1, 1); stage_pair(1, 1, 2); }

    int cur = 0;
    for (int t = 0; t < NT; ++t) {
        // wait for tile t's 6 loads; keep tile t+1's 6 in flight (T4)
        if (t + 1 < NT) asm volatile("s_waitcnt vmcnt(6)" ::: "memory");
        else            asm volatile("s_waitcnt vmcnt(0)" ::: "memory");
        __builtin_amdgcn_s_barrier();           // everyone's tile-t loads landed;
        __builtin_amdgcn_sched_barrier(0);      // all reads of buf[(t+2)%3] done

        const int nbuf = (cur + 2 >= 3) ? cur - 1 : cur + 2;
        const bool pf = (t + 2 < NT);

        // B fragments once per K-tile
        bf16x8 bhf[4], blf[4];
#pragma unroll
        for (int n = 0; n < 4; n++) {
            int ro = (wc + n * 16 + r16) * 32 + g * 8;
            bhf[n] = __builtin_bit_cast(bf16x8, *(const ushort8*)&sBh[cur][ro]);
            blf[n] = __builtin_bit_cast(bf16x8, *(const ushort8*)&sBl[cur][ro]);
        }
#pragma unroll
        for (int m = 0; m < 4; m++) {
            int ro = (wr + m * 16 + r16) * 32 + g * 8;
            bf16x8 ahf = __builtin_bit_cast(bf16x8, *(const ushort8*)&sAh[cur][ro]);
            bf16x8 alf = __builtin_bit_cast(bf16x8, *(const ushort8*)&sAl[cur][ro]);
            if (m < 3 && pf) stage_pair(nbuf, t + 2, m);   // 2 prefetch loads/phase
            asm volatile("s_waitcnt lgkmcnt(0)" ::: "memory");
            __builtin_amdgcn_sched_barrier(0);
            __builtin_amdgcn_s_setprio(1);
#pragma unroll
            for (int n = 0; n < 4; n++)
                acc[m][n] = __builtin_amdgcn_mfma_f32_16x16x32_bf16(ahf, bhf[n], acc[m][n], 0, 0, 0);
#pragma unroll
            for (int n = 0; n < 4; n++)
                acc[m][n] = __builtin_amdgcn_mfma_f32_16x16x32_bf16(ahf, blf[n], acc[m][n], 0, 0, 0);
#pragma unroll
            for (int n = 0; n < 4; n++)
                acc[m][n] = __builtin_amdgcn_mfma_f32_16x16x32_bf16(alf, bhf[n], acc[m][n], 0, 0, 0);
            __builtin_amdgcn_s_setprio(0);
        }
        cur = (cur + 1 >= 3) ? 0 : cur + 1;
    }

#pragma unroll
    for (int m = 0; m < 4; m++)
#pragma unroll
        for (int n = 0; n < 4; n++) {
            int col = bcol0 + wc + n * 16 + r16;
#pragma unroll
            for (int j = 0; j < 4; j++) {
                int row = arow0 + wr + m * 16 + g * 4 + j;
                float v = acc[m][n][j];
                if (EPI == 0) {
                    unsigned short h = f2bf(v);
                    Ch[(size_t)row * N + col] = h;
                    Cl[(size_t)row * N + col] = f2bf(v - bf2f(h));
                } else {
                    Cf[(size_t)row * N + col] = v + bias[col];
                }
            }
        }
}

// ---------------------------------------------------------------------------
// 4) RoPE in place on qkv hi/lo (cols 0..4095 = q,k), one block per (b,t) row
// ---------------------------------------------------------------------------
__global__ __launch_bounds__(256) void k_rope(unsigned short* __restrict__ qh,
                                              unsigned short* __restrict__ ql) {
    __shared__ float row[4096];
    __shared__ float cs[64], sn[64];
    const int rb = blockIdx.x;        // b*T + t
    const int t = rb & (TT - 1);
    const int tid = threadIdx.x;
    if (tid < 64) {
        float invf = 1.0f / powf(10000.0f, (float)tid * (1.0f / 64.0f));
        float s, c;
        sincosf((float)t * invf, &s, &c);
        cs[tid] = c; sn[tid] = s;
    }
    const size_t base = (size_t)rb * QKVN;
#pragma unroll
    for (int i = 0; i < 2; i++) {
        int c0 = (tid + i * 256) * 8;
        ushort8 h = *(const ushort8*)&qh[base + c0];
        ushort8 l = *(const ushort8*)&ql[base + c0];
#pragma unroll
        for (int e = 0; e < 8; e++) row[c0 + e] = bf2f(h[e]) + bf2f(l[e]);
    }
    __syncthreads();
#pragma unroll
    for (int i = 0; i < 2; i++) {
        int c0 = (tid + i * 256) * 8;
        int d0 = c0 & 127;
        ushort8 h, l;
#pragma unroll
        for (int e = 0; e < 8; e++) {
            int c = c0 + e, d = d0 + e;
            float x = row[c];
            float xr = (d < 64) ? -row[c + 64] : row[c - 64];
            float v = x * cs[d & 63] + xr * sn[d & 63];
            unsigned short hh = f2bf(v);
            h[e] = hh; l[e] = f2bf(v - bf2f(hh));
        }
        *(ushort8*)&qh[base + c0] = h;
        *(ushort8*)&ql[base + c0] = l;
    }
}

// ---------------------------------------------------------------------------
// 5) extract V^T per head: vt[bh][d][t] = bf16(qkv[b,t, 4096 + h*128 + d])
// ---------------------------------------------------------------------------
__global__ __launch_bounds__(128) void k_vt(const unsigned short* __restrict__ qkvh,
                                            unsigned short* __restrict__ vt) {
    const int bh = blockIdx.x;    // 0..31
    const int tc = blockIdx.y;    // 0..31 (chunk of 64 t's)
    const int d = threadIdx.x;    // 0..127
    const int b = bh >> 4, h = bh & 15;
    unsigned short buf[64];
    const size_t src0 = ((size_t)(b * TT + tc * 64)) * QKVN + 4096 + h * 128 + d;
#pragma unroll
    for (int ttt = 0; ttt < 64; ttt++) buf[ttt] = qkvh[src0 + (size_t)ttt * QKVN];
    const size_t dst = ((size_t)bh * 128 + d) * TT + tc * 64;
#pragma unroll
    for (int i = 0; i < 8; i++)
        *(ushort8*)&vt[dst + i * 8] = *(const ushort8*)&buf[i * 8];
}

// ---------------------------------------------------------------------------
// 6) causal flash attention v2 (unchanged from R2: QBLK=64, KVBLK=64,
//    double-buffered staging, XCD remap, heavy-qb-first).
// ---------------------------------------------------------------------------
__global__ __launch_bounds__(256) void k_flash(const unsigned short* __restrict__ qkvh,
                                               const unsigned short* __restrict__ vt,
                                               unsigned short* __restrict__ aoh,
                                               unsigned short* __restrict__ aol) {
    __shared__ unsigned short sK[2][64 * 128];
    __shared__ unsigned short sV[2][128 * 64];
    __shared__ unsigned short sP[4][16 * 64];

    const int L = blockIdx.y * gridDim.x + blockIdx.x;
    const int logical = (L & 7) * 128 + (L >> 3);
    const int bh = logical >> 5;
    const int qb = 31 - (logical & 31);
    const int b = bh >> 4, h = bh & 15;

    const int tid = threadIdx.x, wave = tid >> 6, lane = tid & 63;
    const int g = lane >> 4, r16 = lane & 15;
    const float scale = 0.08838834764831845f;   // 1/sqrt(128)

    bf16x8 qf[4];
    {
        const int qrow = qb * 64 + wave * 16 + r16;
        const size_t qbase = ((size_t)(b * TT) + qrow) * QKVN + h * 128;
#pragma unroll
        for (int kk = 0; kk < 4; kk++) {
            ushort8 u = *(const ushort8*)&qkvh[qbase + kk * 32 + g * 8];
            ushort8 o;
#pragma unroll
            for (int e = 0; e < 8; e++) o[e] = f2bf(bf2f(u[e]) * scale);
            qf[kk] = __builtin_bit_cast(bf16x8, o);
        }
    }

    f32x4 oacc[8];
#pragma unroll
    for (int n = 0; n < 8; n++) oacc[n] = (f32x4){0.f, 0.f, 0.f, 0.f};
    float mrun[4], lrun[4];
#pragma unroll
    for (int j = 0; j < 4; j++) { mrun[j] = -1e30f; lrun[j] = 0.f; }

    const int k_row_st = wave * 4 + (lane >> 4);    // + i*16 ; slot = lane&15
    const int v_row_st = wave * 8 + (lane >> 3);    // + i*32 ; slot = lane&7
    const int lidx = wave * 512 + lane * 8;

    auto stage = [&](int buf, int kb) {
#pragma unroll
        for (int i = 0; i < 4; i++) {
            int krow = i * 16 + k_row_st;
            int kcol = ((lane & 15) ^ (krow & 7)) << 3;
            GLOAD16(qkvh + ((size_t)(b * TT + kb * 64 + krow)) * QKVN + 2048 + h * 128 + kcol,
                    &sK[buf][i * 2048 + lidx]);
            int vrow = i * 32 + v_row_st;
            int vcol = ((lane & 7) ^ (vrow & 7)) << 3;
            GLOAD16(vt + ((size_t)bh * 128 + vrow) * TT + kb * 64 + vcol,
                    &sV[buf][i * 2048 + lidx]);
        }
    };

    const int nkb = qb + 1;
    int cur = 0;
    stage(0, 0);

    for (int kb = 0; kb < nkb; kb++) {
        __syncthreads();
        if (kb + 1 < nkb) stage(cur ^ 1, kb + 1);

        f32x4 sacc[4];
#pragma unroll
        for (int n = 0; n < 4; n++) sacc[n] = (f32x4){0.f, 0.f, 0.f, 0.f};
#pragma unroll
        for (int n = 0; n < 4; n++) {
            const int krow = n * 16 + r16;
            const int rbase = krow * 128;
            const int sw = krow & 7;
#pragma unroll
            for (int kk = 0; kk < 4; kk++) {
                int slot = (kk * 4 + g) ^ sw;
                bf16x8 kf = __builtin_bit_cast(bf16x8, *(const ushort8*)&sK[cur][rbase + slot * 8]);
                sacc[n] = __builtin_amdgcn_mfma_f32_16x16x32_bf16(qf[kk], kf, sacc[n], 0, 0, 0);
            }
        }

        const int key0 = kb * 64;
#pragma unroll
        for (int j = 0; j < 4; j++) {
            const int prow = g * 4 + j;
            const int qg = qb * 64 + wave * 16 + prow;
            float s0 = sacc[0][j], s1 = sacc[1][j], s2 = sacc[2][j], s3 = sacc[3][j];
            if (kb == qb) {
                if (key0 + r16 > qg)      s0 = -1e30f;
                if (key0 + 16 + r16 > qg) s1 = -1e30f;
                if (key0 + 32 + r16 > qg) s2 = -1e30f;
                if (key0 + 48 + r16 > qg) s3 = -1e30f;
            }
            float tmax = fmaxf(fmaxf(s0, s1), fmaxf(s2, s3));
#pragma unroll
            for (int off = 8; off >= 1; off >>= 1) tmax = fmaxf(tmax, __shfl_xor(tmax, off));
            float mnew = fmaxf(mrun[j], tmax);
            float corr = __expf(mrun[j] - mnew);
            float p0 = __expf(s0 - mnew), p1 = __expf(s1 - mnew);
            float p2 = __expf(s2 - mnew), p3 = __expf(s3 - mnew);
            float rs = (p0 + p1) + (p2 + p3);
#pragma unroll
            for (int off = 8; off >= 1; off >>= 1) rs += __shfl_xor(rs, off);
            lrun[j] = lrun[j] * corr + rs;
            mrun[j] = mnew;
#pragma unroll
            for (int n = 0; n < 8; n++) oacc[n][j] *= corr;
            const int pb = prow * 64, sw = prow & 7, e = r16 & 7, hi2 = (r16 >> 3);
            sP[wave][pb + (((0 + hi2) ^ sw) << 3) + e] = f2bf(p0);
            sP[wave][pb + (((2 + hi2) ^ sw) << 3) + e] = f2bf(p1);
            sP[wave][pb + (((4 + hi2) ^ sw) << 3) + e] = f2bf(p2);
            sP[wave][pb + (((6 + hi2) ^ sw) << 3) + e] = f2bf(p3);
        }

#pragma unroll
        for (int kk = 0; kk < 2; kk++) {
            const int slot = (kk * 4 + g) ^ (r16 & 7);
            bf16x8 pf = __builtin_bit_cast(bf16x8, *(const ushort8*)&sP[wave][r16 * 64 + slot * 8]);
#pragma unroll
            for (int n = 0; n < 8; n++) {
                const int d = n * 16 + r16;
                bf16x8 vf = __builtin_bit_cast(bf16x8, *(const ushort8*)&sV[cur][d * 64 + slot * 8]);
                oacc[n] = __builtin_amdgcn_mfma_f32_16x16x32_bf16(pf, vf, oacc[n], 0, 0, 0);
            }
        }
        cur ^= 1;
    }

#pragma unroll
    for (int j = 0; j < 4; j++) {
        float inv = 1.0f / lrun[j];
        int qg = qb * 64 + wave * 16 + g * 4 + j;
        size_t obase = ((size_t)(b * TT) + qg) * DM + h * 128;
#pragma unroll
        for (int n = 0; n < 8; n++) {
            float v = oacc[n][j] * inv;
            unsigned short hh = f2bf(v);
            aoh[obase + n * 16 + r16] = hh;
            aol[obase + n * 16 + r16] = f2bf(v - bf2f(hh));
        }
    }
}

// ---------------------------------------------------------------------------
extern "C" void kernel_launch(void* const* d_in, const int* in_sizes, int n_in,
                              void* d_out, int out_size, void* d_ws, size_t ws_size,
                              hipStream_t stream) {
    const float* x = (const float*)d_in[0];
    const float* Wqkv = (const float*)d_in[1];
    const float* Wproj = (const float*)d_in[2];
    const float* bproj = (const float*)d_in[3];
    // d_in[4] = mask (causal structure implemented directly)

    uint8_t* w = (uint8_t*)d_ws;
    auto alloc = [&](size_t bytes) { uint8_t* p = w; w += bytes; return p; };
    unsigned short* xh   = (unsigned short*)alloc(8388608ull * 2);   // x hi
    unsigned short* xl   = (unsigned short*)alloc(8388608ull * 2);   // x lo
    unsigned short* wqh  = (unsigned short*)alloc(12582912ull * 2);  // WqkvT hi [6144][2048]
    unsigned short* wql  = (unsigned short*)alloc(12582912ull * 2);
    unsigned short* wph  = (unsigned short*)alloc(4194304ull * 2);   // WprojT hi [2048][2048]
    unsigned short* wpl  = (unsigned short*)alloc(4194304ull * 2);
    unsigned short* qkvh = (unsigned short*)alloc(25165824ull * 2);  // qkv hi [4096][6144]
    unsigned short* qkvl = (unsigned short*)alloc(25165824ull * 2);
    unsigned short* vtp  = (unsigned short*)alloc(8388608ull * 2);   // V^T [32][128][2048]
    unsigned short* aoh  = (unsigned short*)alloc(8388608ull * 2);   // attn out hi [4096][2048]
    unsigned short* aol  = (unsigned short*)alloc(8388608ull * 2);

    k_split<<<dim3(8192), dim3(256), 0, stream>>>(x, xh, xl, 2097152);
    k_tsplit<<<dim3(192, 64), dim3(32, 8), 0, stream>>>(Wqkv, wqh, wql, 2048, 6144);
    k_tsplit<<<dim3(64, 64), dim3(32, 8), 0, stream>>>(Wproj, wph, wpl, 2048, 2048);
    k_gemm<0><<<dim3(48, 16), dim3(512), 0, stream>>>(xh, xl, wqh, wql,
                                                      qkvh, qkvl, nullptr, nullptr,
                                                      4096, 6144, 2048);
    k_rope<<<dim3(4096), dim3(256), 0, stream>>>(qkvh, qkvl);
    k_vt<<<dim3(32, 32), dim3(128), 0, stream>>>(qkvh, vtp);
    k_flash<<<dim3(32, 32), dim3(256), 0, stream>>>(qkvh, vtp, aoh, aol);
    k_gemm<1><<<dim3(16, 16), dim3(512), 0, stream>>>(aoh, aol, wph, wpl,
                                                      nullptr, nullptr,
                                                      (float*)d_out, bproj,
                                                      4096, 2048, 2048);
}

// Round 4
// 589.839 us; speedup vs baseline: 1.3859x; 1.2105x over previous
//
#include <hip/hip_runtime.h>
#include <cstdint>

// Problem constants
#define BB 2
#define TT 2048
#define DM 2048
#define NH 16
#define HD 128
#define QKVN 6144   // 3*DM

using f32x4   = __attribute__((ext_vector_type(4))) float;
using bf16x8  = __attribute__((ext_vector_type(8))) __bf16;
using ushort8 = __attribute__((ext_vector_type(8))) unsigned short;

static __device__ __forceinline__ unsigned short f2bf(float f) {
    uint32_t u = __builtin_bit_cast(uint32_t, f);
    u += 0x7FFFu + ((u >> 16) & 1u);          // RNE
    return (unsigned short)(u >> 16);
}
static __device__ __forceinline__ float bf2f(unsigned short h) {
    return __builtin_bit_cast(float, ((uint32_t)h) << 16);
}

#define GLOAD16(SRC, DST)                                               \
    __builtin_amdgcn_global_load_lds(                                   \
        (const __attribute__((address_space(1))) void*)(SRC),           \
        (__attribute__((address_space(3))) void*)(DST), 16, 0, 0)

// ---------------------------------------------------------------------------
// 1) elementwise fp32 -> bf16 hi/lo split (for x)
// ---------------------------------------------------------------------------
__global__ __launch_bounds__(256) void k_split(const float* __restrict__ in,
                                               unsigned short* __restrict__ hi,
                                               unsigned short* __restrict__ lo,
                                               int n4) {
    int i = blockIdx.x * 256 + threadIdx.x;
    if (i >= n4) return;
    float4 v = reinterpret_cast<const float4*>(in)[i];
    ushort4 h, l;
    h.x = f2bf(v.x); l.x = f2bf(v.x - bf2f(h.x));
    h.y = f2bf(v.y); l.y = f2bf(v.y - bf2f(h.y));
    h.z = f2bf(v.z); l.z = f2bf(v.z - bf2f(h.z));
    h.w = f2bf(v.w); l.w = f2bf(v.w - bf2f(h.w));
    reinterpret_cast<ushort4*>(hi)[i] = h;
    reinterpret_cast<ushort4*>(lo)[i] = l;
}

// ---------------------------------------------------------------------------
// 2) W [K,N] fp32 -> Wt hi [N,K] bf16  (transpose, hi only — 2-term split
//    keeps B single-precision bf16; its rounding error ~5e-4 absolute)
// ---------------------------------------------------------------------------
__global__ __launch_bounds__(256) void k_tsplit(const float* __restrict__ W,
                                                unsigned short* __restrict__ th,
                                                int K, int N) {
    __shared__ float tile[32][33];
    int bn = blockIdx.x * 32, bk = blockIdx.y * 32;
    int tx = threadIdx.x, ty = threadIdx.y;   // 32 x 8
#pragma unroll
    for (int r = 0; r < 4; r++)
        tile[ty + 8 * r][tx] = W[(size_t)(bk + ty + 8 * r) * N + bn + tx];
    __syncthreads();
#pragma unroll
    for (int r = 0; r < 4; r++) {
        float v = tile[tx][ty + 8 * r];
        int row = bn + ty + 8 * r, col = bk + tx;
        th[(size_t)row * K + col] = f2bf(v);
    }
}

// ---------------------------------------------------------------------------
// 3) split-bf16 GEMM v3:  C[M,N] = (Ah+Al)[M,K] * Bh^T  (2-term split-A)
//    BM=256, BN=128, BK=64, 8 waves (4m x 2n), 64x64/wave, 4x4 acc.
//    Double-buffered LDS (exactly 160 KB), XOR-swizzled rows (slot^=row&7,
//    pre-swizzled global source for global_load_lds), counted lgkmcnt(12/0)
//    before each 32-MFMA cluster, vmcnt(0) only at bottom (T3-minimum),
//    setprio around MFMA, bijective XCD swizzle.
//    EPI 0: write C as bf16 hi.  EPI 1: write fp32 C + bias.
// ---------------------------------------------------------------------------
template <int EPI>
__global__ __launch_bounds__(512, 2) void k_gemm(
    const unsigned short* __restrict__ Ah, const unsigned short* __restrict__ Al,
    const unsigned short* __restrict__ Bh,
    unsigned short* __restrict__ Ch,
    float* __restrict__ Cf, const float* __restrict__ bias,
    int M, int N, int K) {
    __shared__ unsigned short sAh[2][16384];   // 256 rows x 64 (8 slots of 8)
    __shared__ unsigned short sAl[2][16384];
    __shared__ unsigned short sBh[2][8192];    // 128 rows x 64

    // T1: bijective XCD swizzle (both grids have nwg % 8 == 0)
    const int nwg = gridDim.x * gridDim.y;
    const int L = blockIdx.y * gridDim.x + blockIdx.x;
    const int logical = (L & 7) * (nwg >> 3) + (L >> 3);
    const int bx = logical % gridDim.x, by = logical / gridDim.x;

    const int tid = threadIdx.x;
    const int wave = tid >> 6, lane = tid & 63;
    const int g = lane >> 4, r16 = lane & 15;
    const int arow0 = by * 256, bcol0 = bx * 128;
    const int wr = (wave >> 1) * 64, wc = (wave & 1) * 64;
    const int sw8 = r16 & 7;                   // fragment-read swizzle

    // staging: load slot S = i*512 + tid -> row = i*64 + (tid>>3), slot = tid&7
    // source col pre-swizzled: (slot ^ (row&7))*8 ; row&7 == (tid>>3)&7
    const int srow = tid >> 3;
    const int scol = ((tid & 7) ^ (srow & 7)) << 3;

    f32x4 acc[4][4];
#pragma unroll
    for (int m = 0; m < 4; m++)
#pragma unroll
        for (int n = 0; n < 4; n++) acc[m][n] = (f32x4){0.f, 0.f, 0.f, 0.f};

    const int NT = K >> 6;

    auto stage = [&](int buf, int tk) {
        const size_t kof = (size_t)tk * 64 + scol;
#pragma unroll
        for (int i = 0; i < 4; i++) {
            size_t off = (size_t)(arow0 + i * 64 + srow) * K + kof;
            GLOAD16(Ah + off, &sAh[buf][(i * 512 + tid) * 8]);
            GLOAD16(Al + off, &sAl[buf][(i * 512 + tid) * 8]);
        }
#pragma unroll
        for (int i = 0; i < 2; i++) {
            size_t off = (size_t)(bcol0 + i * 64 + srow) * K + kof;
            GLOAD16(Bh + off, &sBh[buf][(i * 512 + tid) * 8]);
        }
    };

    // prologue
    stage(0, 0);
    asm volatile("s_waitcnt vmcnt(0)" ::: "memory");
    __builtin_amdgcn_s_barrier();

    int cur = 0;
    for (int t = 0; t < NT; ++t) {
        bf16x8 ah0[4], al0[4], bh0[4], ah1[4], al1[4], bh1[4];
        // group0 ds_reads (kstep 0): 12
#pragma unroll
        for (int m = 0; m < 4; m++) {
            int ro = (wr + m * 16 + r16) * 64 + ((g ^ sw8) << 3);
            ah0[m] = __builtin_bit_cast(bf16x8, *(const ushort8*)&sAh[cur][ro]);
            al0[m] = __builtin_bit_cast(bf16x8, *(const ushort8*)&sAl[cur][ro]);
        }
#pragma unroll
        for (int n = 0; n < 4; n++) {
            int ro = (wc + n * 16 + r16) * 64 + ((g ^ sw8) << 3);
            bh0[n] = __builtin_bit_cast(bf16x8, *(const ushort8*)&sBh[cur][ro]);
        }
        __builtin_amdgcn_sched_barrier(0);
        if (t + 1 < NT) stage(cur ^ 1, t + 1);      // prefetch during compute
        __builtin_amdgcn_sched_barrier(0);
        // group1 ds_reads (kstep 1): 12
#pragma unroll
        for (int m = 0; m < 4; m++) {
            int ro = (wr + m * 16 + r16) * 64 + (((4 + g) ^ sw8) << 3);
            ah1[m] = __builtin_bit_cast(bf16x8, *(const ushort8*)&sAh[cur][ro]);
            al1[m] = __builtin_bit_cast(bf16x8, *(const ushort8*)&sAl[cur][ro]);
        }
#pragma unroll
        for (int n = 0; n < 4; n++) {
            int ro = (wc + n * 16 + r16) * 64 + (((4 + g) ^ sw8) << 3);
            bh1[n] = __builtin_bit_cast(bf16x8, *(const ushort8*)&sBh[cur][ro]);
        }
        __builtin_amdgcn_sched_barrier(0);
        asm volatile("s_waitcnt lgkmcnt(12)" ::: "memory");   // group0 landed
        __builtin_amdgcn_sched_barrier(0);
        __builtin_amdgcn_s_setprio(1);
#pragma unroll
        for (int m = 0; m < 4; m++)
#pragma unroll
            for (int n = 0; n < 4; n++) {
                acc[m][n] = __builtin_amdgcn_mfma_f32_16x16x32_bf16(ah0[m], bh0[n], acc[m][n], 0, 0, 0);
                acc[m][n] = __builtin_amdgcn_mfma_f32_16x16x32_bf16(al0[m], bh0[n], acc[m][n], 0, 0, 0);
            }
        __builtin_amdgcn_s_setprio(0);
        asm volatile("s_waitcnt lgkmcnt(0)" ::: "memory");    // group1 landed
        __builtin_amdgcn_sched_barrier(0);
        __builtin_amdgcn_s_setprio(1);
#pragma unroll
        for (int m = 0; m < 4; m++)
#pragma unroll
            for (int n = 0; n < 4; n++) {
                acc[m][n] = __builtin_amdgcn_mfma_f32_16x16x32_bf16(ah1[m], bh1[n], acc[m][n], 0, 0, 0);
                acc[m][n] = __builtin_amdgcn_mfma_f32_16x16x32_bf16(al1[m], bh1[n], acc[m][n], 0, 0, 0);
            }
        __builtin_amdgcn_s_setprio(0);
        asm volatile("s_waitcnt vmcnt(0)" ::: "memory");      // next tile landed
        __builtin_amdgcn_s_barrier();
        cur ^= 1;
    }

#pragma unroll
    for (int m = 0; m < 4; m++)
#pragma unroll
        for (int n = 0; n < 4; n++) {
            int col = bcol0 + wc + n * 16 + r16;
#pragma unroll
            for (int j = 0; j < 4; j++) {
                int row = arow0 + wr + m * 16 + g * 4 + j;
                float v = acc[m][n][j];
                if (EPI == 0) {
                    Ch[(size_t)row * N + col] = f2bf(v);
                } else {
                    Cf[(size_t)row * N + col] = v + bias[col];
                }
            }
        }
}

// ---------------------------------------------------------------------------
// 4) RoPE in place on qkv hi (cols 0..4095 = q,k), one block per (b,t) row
// ---------------------------------------------------------------------------
__global__ __launch_bounds__(256) void k_rope(unsigned short* __restrict__ qh) {
    __shared__ float row[4096];
    __shared__ float cs[64], sn[64];
    const int rb = blockIdx.x;        // b*T + t
    const int t = rb & (TT - 1);
    const int tid = threadIdx.x;
    if (tid < 64) {
        float invf = 1.0f / powf(10000.0f, (float)tid * (1.0f / 64.0f));
        float s, c;
        sincosf((float)t * invf, &s, &c);
        cs[tid] = c; sn[tid] = s;
    }
    const size_t base = (size_t)rb * QKVN;
#pragma unroll
    for (int i = 0; i < 2; i++) {
        int c0 = (tid + i * 256) * 8;
        ushort8 h = *(const ushort8*)&qh[base + c0];
#pragma unroll
        for (int e = 0; e < 8; e++) row[c0 + e] = bf2f(h[e]);
    }
    __syncthreads();
#pragma unroll
    for (int i = 0; i < 2; i++) {
        int c0 = (tid + i * 256) * 8;
        int d0 = c0 & 127;
        ushort8 h;
#pragma unroll
        for (int e = 0; e < 8; e++) {
            int c = c0 + e, d = d0 + e;
            float x = row[c];
            float xr = (d < 64) ? -row[c + 64] : row[c - 64];
            float v = x * cs[d & 63] + xr * sn[d & 63];
            h[e] = f2bf(v);
        }
        *(ushort8*)&qh[base + c0] = h;
    }
}

// ---------------------------------------------------------------------------
// 5) extract V^T per head: vt[bh][d][t] = bf16(qkv[b,t, 4096 + h*128 + d])
// ---------------------------------------------------------------------------
__global__ __launch_bounds__(128) void k_vt(const unsigned short* __restrict__ qkvh,
                                            unsigned short* __restrict__ vt) {
    const int bh = blockIdx.x;    // 0..31
    const int tc = blockIdx.y;    // 0..31 (chunk of 64 t's)
    const int d = threadIdx.x;    // 0..127
    const int b = bh >> 4, h = bh & 15;
    unsigned short buf[64];
    const size_t src0 = ((size_t)(b * TT + tc * 64)) * QKVN + 4096 + h * 128 + d;
#pragma unroll
    for (int ttt = 0; ttt < 64; ttt++) buf[ttt] = qkvh[src0 + (size_t)ttt * QKVN];
    const size_t dst = ((size_t)bh * 128 + d) * TT + tc * 64;
#pragma unroll
    for (int i = 0; i < 8; i++)
        *(ushort8*)&vt[dst + i * 8] = *(const ushort8*)&buf[i * 8];
}

// ---------------------------------------------------------------------------
// 6) causal flash attention (unchanged from R2: QBLK=64, KVBLK=64,
//    double-buffered staging, XCD remap, heavy-qb-first).
// ---------------------------------------------------------------------------
__global__ __launch_bounds__(256) void k_flash(const unsigned short* __restrict__ qkvh,
                                               const unsigned short* __restrict__ vt,
                                               unsigned short* __restrict__ aoh,
                                               unsigned short* __restrict__ aol) {
    __shared__ unsigned short sK[2][64 * 128];
    __shared__ unsigned short sV[2][128 * 64];
    __shared__ unsigned short sP[4][16 * 64];

    const int L = blockIdx.y * gridDim.x + blockIdx.x;
    const int logical = (L & 7) * 128 + (L >> 3);
    const int bh = logical >> 5;
    const int qb = 31 - (logical & 31);
    const int b = bh >> 4, h = bh & 15;

    const int tid = threadIdx.x, wave = tid >> 6, lane = tid & 63;
    const int g = lane >> 4, r16 = lane & 15;
    const float scale = 0.08838834764831845f;   // 1/sqrt(128)

    bf16x8 qf[4];
    {
        const int qrow = qb * 64 + wave * 16 + r16;
        const size_t qbase = ((size_t)(b * TT) + qrow) * QKVN + h * 128;
#pragma unroll
        for (int kk = 0; kk < 4; kk++) {
            ushort8 u = *(const ushort8*)&qkvh[qbase + kk * 32 + g * 8];
            ushort8 o;
#pragma unroll
            for (int e = 0; e < 8; e++) o[e] = f2bf(bf2f(u[e]) * scale);
            qf[kk] = __builtin_bit_cast(bf16x8, o);
        }
    }

    f32x4 oacc[8];
#pragma unroll
    for (int n = 0; n < 8; n++) oacc[n] = (f32x4){0.f, 0.f, 0.f, 0.f};
    float mrun[4], lrun[4];
#pragma unroll
    for (int j = 0; j < 4; j++) { mrun[j] = -1e30f; lrun[j] = 0.f; }

    const int k_row_st = wave * 4 + (lane >> 4);    // + i*16 ; slot = lane&15
    const int v_row_st = wave * 8 + (lane >> 3);    // + i*32 ; slot = lane&7
    const int lidx = wave * 512 + lane * 8;

    auto stage = [&](int buf, int kb) {
#pragma unroll
        for (int i = 0; i < 4; i++) {
            int krow = i * 16 + k_row_st;
            int kcol = ((lane & 15) ^ (krow & 7)) << 3;
            GLOAD16(qkvh + ((size_t)(b * TT + kb * 64 + krow)) * QKVN + 2048 + h * 128 + kcol,
                    &sK[buf][i * 2048 + lidx]);
            int vrow = i * 32 + v_row_st;
            int vcol = ((lane & 7) ^ (vrow & 7)) << 3;
            GLOAD16(vt + ((size_t)bh * 128 + vrow) * TT + kb * 64 + vcol,
                    &sV[buf][i * 2048 + lidx]);
        }
    };

    const int nkb = qb + 1;
    int cur = 0;
    stage(0, 0);

    for (int kb = 0; kb < nkb; kb++) {
        __syncthreads();
        if (kb + 1 < nkb) stage(cur ^ 1, kb + 1);

        f32x4 sacc[4];
#pragma unroll
        for (int n = 0; n < 4; n++) sacc[n] = (f32x4){0.f, 0.f, 0.f, 0.f};
#pragma unroll
        for (int n = 0; n < 4; n++) {
            const int krow = n * 16 + r16;
            const int rbase = krow * 128;
            const int sw = krow & 7;
#pragma unroll
            for (int kk = 0; kk < 4; kk++) {
                int slot = (kk * 4 + g) ^ sw;
                bf16x8 kf = __builtin_bit_cast(bf16x8, *(const ushort8*)&sK[cur][rbase + slot * 8]);
                sacc[n] = __builtin_amdgcn_mfma_f32_16x16x32_bf16(qf[kk], kf, sacc[n], 0, 0, 0);
            }
        }

        const int key0 = kb * 64;
#pragma unroll
        for (int j = 0; j < 4; j++) {
            const int prow = g * 4 + j;
            const int qg = qb * 64 + wave * 16 + prow;
            float s0 = sacc[0][j], s1 = sacc[1][j], s2 = sacc[2][j], s3 = sacc[3][j];
            if (kb == qb) {
                if (key0 + r16 > qg)      s0 = -1e30f;
                if (key0 + 16 + r16 > qg) s1 = -1e30f;
                if (key0 + 32 + r16 > qg) s2 = -1e30f;
                if (key0 + 48 + r16 > qg) s3 = -1e30f;
            }
            float tmax = fmaxf(fmaxf(s0, s1), fmaxf(s2, s3));
#pragma unroll
            for (int off = 8; off >= 1; off >>= 1) tmax = fmaxf(tmax, __shfl_xor(tmax, off));
            float mnew = fmaxf(mrun[j], tmax);
            float corr = __expf(mrun[j] - mnew);
            float p0 = __expf(s0 - mnew), p1 = __expf(s1 - mnew);
            float p2 = __expf(s2 - mnew), p3 = __expf(s3 - mnew);
            float rs = (p0 + p1) + (p2 + p3);
#pragma unroll
            for (int off = 8; off >= 1; off >>= 1) rs += __shfl_xor(rs, off);
            lrun[j] = lrun[j] * corr + rs;
            mrun[j] = mnew;
#pragma unroll
            for (int n = 0; n < 8; n++) oacc[n][j] *= corr;
            const int pb = prow * 64, sw = prow & 7, e = r16 & 7, hi2 = (r16 >> 3);
            sP[wave][pb + (((0 + hi2) ^ sw) << 3) + e] = f2bf(p0);
            sP[wave][pb + (((2 + hi2) ^ sw) << 3) + e] = f2bf(p1);
            sP[wave][pb + (((4 + hi2) ^ sw) << 3) + e] = f2bf(p2);
            sP[wave][pb + (((6 + hi2) ^ sw) << 3) + e] = f2bf(p3);
        }

#pragma unroll
        for (int kk = 0; kk < 2; kk++) {
            const int slot = (kk * 4 + g) ^ (r16 & 7);
            bf16x8 pf = __builtin_bit_cast(bf16x8, *(const ushort8*)&sP[wave][r16 * 64 + slot * 8]);
#pragma unroll
            for (int n = 0; n < 8; n++) {
                const int d = n * 16 + r16;
                bf16x8 vf = __builtin_bit_cast(bf16x8, *(const ushort8*)&sV[cur][d * 64 + slot * 8]);
                oacc[n] = __builtin_amdgcn_mfma_f32_16x16x32_bf16(pf, vf, oacc[n], 0, 0, 0);
            }
        }
        cur ^= 1;
    }

#pragma unroll
    for (int j = 0; j < 4; j++) {
        float inv = 1.0f / lrun[j];
        int qg = qb * 64 + wave * 16 + g * 4 + j;
        size_t obase = ((size_t)(b * TT) + qg) * DM + h * 128;
#pragma unroll
        for (int n = 0; n < 8; n++) {
            float v = oacc[n][j] * inv;
            unsigned short hh = f2bf(v);
            aoh[obase + n * 16 + r16] = hh;
            aol[obase + n * 16 + r16] = f2bf(v - bf2f(hh));
        }
    }
}

// ---------------------------------------------------------------------------
extern "C" void kernel_launch(void* const* d_in, const int* in_sizes, int n_in,
                              void* d_out, int out_size, void* d_ws, size_t ws_size,
                              hipStream_t stream) {
    const float* x = (const float*)d_in[0];
    const float* Wqkv = (const float*)d_in[1];
    const float* Wproj = (const float*)d_in[2];
    const float* bproj = (const float*)d_in[3];
    // d_in[4] = mask (causal structure implemented directly)

    uint8_t* w = (uint8_t*)d_ws;
    auto alloc = [&](size_t bytes) { uint8_t* p = w; w += bytes; return p; };
    unsigned short* xh   = (unsigned short*)alloc(8388608ull * 2);   // x hi
    unsigned short* xl   = (unsigned short*)alloc(8388608ull * 2);   // x lo
    unsigned short* wqh  = (unsigned short*)alloc(12582912ull * 2);  // WqkvT hi [6144][2048]
    unsigned short* wph  = (unsigned short*)alloc(4194304ull * 2);   // WprojT hi [2048][2048]
    unsigned short* qkvh = (unsigned short*)alloc(25165824ull * 2);  // qkv hi [4096][6144]
    unsigned short* vtp  = (unsigned short*)alloc(8388608ull * 2);   // V^T [32][128][2048]
    unsigned short* aoh  = (unsigned short*)alloc(8388608ull * 2);   // attn out hi [4096][2048]
    unsigned short* aol  = (unsigned short*)alloc(8388608ull * 2);

    k_split<<<dim3(8192), dim3(256), 0, stream>>>(x, xh, xl, 2097152);
    k_tsplit<<<dim3(192, 64), dim3(32, 8), 0, stream>>>(Wqkv, wqh, 2048, 6144);
    k_tsplit<<<dim3(64, 64), dim3(32, 8), 0, stream>>>(Wproj, wph, 2048, 2048);
    k_gemm<0><<<dim3(48, 16), dim3(512), 0, stream>>>(xh, xl, wqh,
                                                      qkvh, nullptr, nullptr,
                                                      4096, 6144, 2048);
    k_rope<<<dim3(4096), dim3(256), 0, stream>>>(qkvh);
    k_vt<<<dim3(32, 32), dim3(128), 0, stream>>>(qkvh, vtp);
    k_flash<<<dim3(32, 32), dim3(256), 0, stream>>>(qkvh, vtp, aoh, aol);
    k_gemm<1><<<dim3(16, 16), dim3(512), 0, stream>>>(aoh, aol, wph,
                                                      nullptr, (float*)d_out, bproj,
                                                      4096, 2048, 2048);
}

// Round 6
// 559.605 us; speedup vs baseline: 1.4607x; 1.0540x over previous
//
#include <hip/hip_runtime.h>
#include <cstdint>

// Problem constants
#define BB 2
#define TT 2048
#define DM 2048
#define NH 16
#define HD 128
#define QKVN 6144   // 3*DM

using f32x4   = __attribute__((ext_vector_type(4))) float;
using bf16x8  = __attribute__((ext_vector_type(8))) __bf16;
using ushort8 = __attribute__((ext_vector_type(8))) unsigned short;

static __device__ __forceinline__ unsigned short f2bf(float f) {
    uint32_t u = __builtin_bit_cast(uint32_t, f);
    u += 0x7FFFu + ((u >> 16) & 1u);          // RNE
    return (unsigned short)(u >> 16);
}
static __device__ __forceinline__ float bf2f(unsigned short h) {
    return __builtin_bit_cast(float, ((uint32_t)h) << 16);
}

#define GLOAD16(SRC, DST)                                               \
    __builtin_amdgcn_global_load_lds(                                   \
        (const __attribute__((address_space(1))) void*)(SRC),           \
        (__attribute__((address_space(3))) void*)(DST), 16, 0, 0)

// ---------------------------------------------------------------------------
// 1) elementwise fp32 -> bf16 hi/lo split (for x)
// ---------------------------------------------------------------------------
__global__ __launch_bounds__(256) void k_split(const float* __restrict__ in,
                                               unsigned short* __restrict__ hi,
                                               unsigned short* __restrict__ lo,
                                               int n4) {
    int i = blockIdx.x * 256 + threadIdx.x;
    if (i >= n4) return;
    float4 v = reinterpret_cast<const float4*>(in)[i];
    ushort4 h, l;
    h.x = f2bf(v.x); l.x = f2bf(v.x - bf2f(h.x));
    h.y = f2bf(v.y); l.y = f2bf(v.y - bf2f(h.y));
    h.z = f2bf(v.z); l.z = f2bf(v.z - bf2f(h.z));
    h.w = f2bf(v.w); l.w = f2bf(v.w - bf2f(h.w));
    reinterpret_cast<ushort4*>(hi)[i] = h;
    reinterpret_cast<ushort4*>(lo)[i] = l;
}

// ---------------------------------------------------------------------------
// 2) W [K,N] fp32 -> Wt hi [N,K] bf16  (transpose, hi only)
// ---------------------------------------------------------------------------
__global__ __launch_bounds__(256) void k_tsplit(const float* __restrict__ W,
                                                unsigned short* __restrict__ th,
                                                int K, int N) {
    __shared__ float tile[32][33];
    int bn = blockIdx.x * 32, bk = blockIdx.y * 32;
    int tx = threadIdx.x, ty = threadIdx.y;   // 32 x 8
#pragma unroll
    for (int r = 0; r < 4; r++)
        tile[ty + 8 * r][tx] = W[(size_t)(bk + ty + 8 * r) * N + bn + tx];
    __syncthreads();
#pragma unroll
    for (int r = 0; r < 4; r++) {
        float v = tile[tx][ty + 8 * r];
        int row = bn + ty + 8 * r, col = bk + tx;
        th[(size_t)row * K + col] = f2bf(v);
    }
}

// ---------------------------------------------------------------------------
// 3) split-bf16 GEMM v4:  C[M,N] = (Ah+Al)[M,K] * Bh^T  (2-term split-A)
//    BM=256, BN=128, BK=64, 8 waves (4m x 2n), 64x64/wave, 4x4 acc.
//    4-phase/K-tile schedule (T3+T4+T5): each phase issues the NEXT chunk's
//    ds_reads + 2-4 staging gloads, waits counted lgkmcnt(4) (1 chunk always
//    in flight), setprio(1) around a 16-MFMA cluster, s_barrier per phase.
//    Double-buffered 160 KB LDS, XOR-swizzled rows, vmcnt(0) only at tile top.
// ---------------------------------------------------------------------------
template <int EPI>
__global__ __launch_bounds__(512, 2) void k_gemm(
    const unsigned short* __restrict__ Ah, const unsigned short* __restrict__ Al,
    const unsigned short* __restrict__ Bh,
    unsigned short* __restrict__ Ch,
    float* __restrict__ Cf, const float* __restrict__ bias,
    int M, int N, int K) {
    __shared__ __align__(16) unsigned short sAh[2][16384];   // 256 rows x 64
    __shared__ __align__(16) unsigned short sAl[2][16384];
    __shared__ __align__(16) unsigned short sBh[2][8192];    // 128 rows x 64

    // T1: bijective XCD swizzle (both grids have nwg % 8 == 0)
    const int nwg = gridDim.x * gridDim.y;
    const int L = blockIdx.y * gridDim.x + blockIdx.x;
    const int logical = (L & 7) * (nwg >> 3) + (L >> 3);
    const int bx = logical % gridDim.x, by = logical / gridDim.x;

    const int tid = threadIdx.x;
    const int wave = tid >> 6, lane = tid & 63;
    const int g = lane >> 4, r16 = lane & 15;
    const int arow0 = by * 256, bcol0 = bx * 128;
    const int wr = (wave >> 1) * 64, wc = (wave & 1) * 64;
    const int sw8 = r16 & 7;                   // fragment-read swizzle

    // staging: thread covers row = i*64 + (tid>>3), slot = tid&7 (pre-swizzled src)
    const int srow = tid >> 3;
    const int scol = ((tid & 7) ^ (srow & 7)) << 3;

    f32x4 acc[4][4];
#pragma unroll
    for (int m = 0; m < 4; m++)
#pragma unroll
        for (int n = 0; n < 4; n++) acc[m][n] = (f32x4){0.f, 0.f, 0.f, 0.f};

    const int NT = K >> 6;

    auto stageA_hi = [&](int buf, int tk) {
        const size_t kof = (size_t)tk * 64 + scol;
#pragma unroll
        for (int i = 0; i < 4; i++)
            GLOAD16(Ah + (size_t)(arow0 + i * 64 + srow) * K + kof,
                    &sAh[buf][(i * 512 + tid) * 8]);
    };
    auto stageA_lo = [&](int buf, int tk) {
        const size_t kof = (size_t)tk * 64 + scol;
#pragma unroll
        for (int i = 0; i < 4; i++)
            GLOAD16(Al + (size_t)(arow0 + i * 64 + srow) * K + kof,
                    &sAl[buf][(i * 512 + tid) * 8]);
    };
    auto stageB = [&](int buf, int tk) {
        const size_t kof = (size_t)tk * 64 + scol;
#pragma unroll
        for (int i = 0; i < 2; i++)
            GLOAD16(Bh + (size_t)(bcol0 + i * 64 + srow) * K + kof,
                    &sBh[buf][(i * 512 + tid) * 8]);
    };

    auto rdA = [&](int buf, int m, int co, bf16x8& h, bf16x8& l) {
        int ro = (wr + m * 16 + r16) * 64 + co;
        h = __builtin_bit_cast(bf16x8, *(const ushort8*)&sAh[buf][ro]);
        l = __builtin_bit_cast(bf16x8, *(const ushort8*)&sAl[buf][ro]);
    };
    auto rdB = [&](int buf, int n, int co) {
        int ro = (wc + n * 16 + r16) * 64 + co;
        return __builtin_bit_cast(bf16x8, *(const ushort8*)&sBh[buf][ro]);
    };

    // prologue: stage tile 0
    stageA_hi(0, 0); stageA_lo(0, 0); stageB(0, 0);

    int cur = 0;
    for (int t = 0; t < NT; ++t) {
        asm volatile("s_waitcnt vmcnt(0)" ::: "memory");   // tile-t staging landed
        __builtin_amdgcn_s_barrier();                      // all reads of buf^1 retired
        const bool pf = (t + 1 < NT);
        const int nb = cur ^ 1;
        const int co0 = (g ^ sw8) << 3, co1 = ((4 + g) ^ sw8) << 3;

        bf16x8 ah0[4], al0[4], bh0[4], ah1[4], al1[4], bh1[4];

        // ---- ph0: issue chunk0 (B k0 + A m01 k0 = 8) + chunk1 (A m23 k0 = 4)
#pragma unroll
        for (int n = 0; n < 4; n++) bh0[n] = rdB(cur, n, co0);
        rdA(cur, 0, co0, ah0[0], al0[0]);
        rdA(cur, 1, co0, ah0[1], al0[1]);
        __builtin_amdgcn_sched_barrier(0);
        rdA(cur, 2, co0, ah0[2], al0[2]);
        rdA(cur, 3, co0, ah0[3], al0[3]);
        __builtin_amdgcn_sched_barrier(0);
        if (pf) stageA_hi(nb, t + 1);
        asm volatile("s_waitcnt lgkmcnt(4)" ::: "memory");  // chunk0 done, chunk1 in flight
        __builtin_amdgcn_sched_barrier(0);
        __builtin_amdgcn_s_setprio(1);
#pragma unroll
        for (int m = 0; m < 2; m++)
#pragma unroll
            for (int n = 0; n < 4; n++) {
                acc[m][n] = __builtin_amdgcn_mfma_f32_16x16x32_bf16(ah0[m], bh0[n], acc[m][n], 0, 0, 0);
                acc[m][n] = __builtin_amdgcn_mfma_f32_16x16x32_bf16(al0[m], bh0[n], acc[m][n], 0, 0, 0);
            }
        __builtin_amdgcn_s_setprio(0);
        __builtin_amdgcn_s_barrier();

        // ---- ph1: issue chunk2 (A m01 k1 = 4)
        rdA(cur, 0, co1, ah1[0], al1[0]);
        rdA(cur, 1, co1, ah1[1], al1[1]);
        __builtin_amdgcn_sched_barrier(0);
        if (pf) stageA_lo(nb, t + 1);
        asm volatile("s_waitcnt lgkmcnt(4)" ::: "memory");  // chunk1 done, chunk2 in flight
        __builtin_amdgcn_sched_barrier(0);
        __builtin_amdgcn_s_setprio(1);
#pragma unroll
        for (int m = 2; m < 4; m++)
#pragma unroll
            for (int n = 0; n < 4; n++) {
                acc[m][n] = __builtin_amdgcn_mfma_f32_16x16x32_bf16(ah0[m], bh0[n], acc[m][n], 0, 0, 0);
                acc[m][n] = __builtin_amdgcn_mfma_f32_16x16x32_bf16(al0[m], bh0[n], acc[m][n], 0, 0, 0);
            }
        __builtin_amdgcn_s_setprio(0);
        __builtin_amdgcn_s_barrier();

        // ---- ph2: issue B k1 (4) then chunk3 (A m23 k1 = 4)
#pragma unroll
        for (int n = 0; n < 4; n++) bh1[n] = rdB(cur, n, co1);
        __builtin_amdgcn_sched_barrier(0);
        rdA(cur, 2, co1, ah1[2], al1[2]);
        rdA(cur, 3, co1, ah1[3], al1[3]);
        __builtin_amdgcn_sched_barrier(0);
        if (pf) stageB(nb, t + 1);
        asm volatile("s_waitcnt lgkmcnt(4)" ::: "memory");  // chunk2 + Bk1 done
        __builtin_amdgcn_sched_barrier(0);
        __builtin_amdgcn_s_setprio(1);
#pragma unroll
        for (int m = 0; m < 2; m++)
#pragma unroll
            for (int n = 0; n < 4; n++) {
                acc[m][n] = __builtin_amdgcn_mfma_f32_16x16x32_bf16(ah1[m], bh1[n], acc[m][n], 0, 0, 0);
                acc[m][n] = __builtin_amdgcn_mfma_f32_16x16x32_bf16(al1[m], bh1[n], acc[m][n], 0, 0, 0);
            }
        __builtin_amdgcn_s_setprio(0);
        __builtin_amdgcn_s_barrier();

        // ---- ph3
        asm volatile("s_waitcnt lgkmcnt(0)" ::: "memory");  // chunk3 done
        __builtin_amdgcn_sched_barrier(0);
        __builtin_amdgcn_s_setprio(1);
#pragma unroll
        for (int m = 2; m < 4; m++)
#pragma unroll
            for (int n = 0; n < 4; n++) {
                acc[m][n] = __builtin_amdgcn_mfma_f32_16x16x32_bf16(ah1[m], bh1[n], acc[m][n], 0, 0, 0);
                acc[m][n] = __builtin_amdgcn_mfma_f32_16x16x32_bf16(al1[m], bh1[n], acc[m][n], 0, 0, 0);
            }
        __builtin_amdgcn_s_setprio(0);
        cur ^= 1;
    }

#pragma unroll
    for (int m = 0; m < 4; m++)
#pragma unroll
        for (int n = 0; n < 4; n++) {
            int col = bcol0 + wc + n * 16 + r16;
#pragma unroll
            for (int j = 0; j < 4; j++) {
                int row = arow0 + wr + m * 16 + g * 4 + j;
                float v = acc[m][n][j];
                if (EPI == 0) {
                    Ch[(size_t)row * N + col] = f2bf(v);
                } else {
                    Cf[(size_t)row * N + col] = v + bias[col];
                }
            }
        }
}

// ---------------------------------------------------------------------------
// 4) RoPE in place on qkv hi (cols 0..4095 = q,k), one block per (b,t) row
// ---------------------------------------------------------------------------
__global__ __launch_bounds__(256) void k_rope(unsigned short* __restrict__ qh) {
    __shared__ float row[4096];
    __shared__ float cs[64], sn[64];
    const int rb = blockIdx.x;        // b*T + t
    const int t = rb & (TT - 1);
    const int tid = threadIdx.x;
    if (tid < 64) {
        float invf = 1.0f / powf(10000.0f, (float)tid * (1.0f / 64.0f));
        float s, c;
        sincosf((float)t * invf, &s, &c);
        cs[tid] = c; sn[tid] = s;
    }
    const size_t base = (size_t)rb * QKVN;
#pragma unroll
    for (int i = 0; i < 2; i++) {
        int c0 = (tid + i * 256) * 8;
        ushort8 h = *(const ushort8*)&qh[base + c0];
#pragma unroll
        for (int e = 0; e < 8; e++) row[c0 + e] = bf2f(h[e]);
    }
    __syncthreads();
#pragma unroll
    for (int i = 0; i < 2; i++) {
        int c0 = (tid + i * 256) * 8;
        int d0 = c0 & 127;
        ushort8 h;
#pragma unroll
        for (int e = 0; e < 8; e++) {
            int c = c0 + e, d = d0 + e;
            float x = row[c];
            float xr = (d < 64) ? -row[c + 64] : row[c - 64];
            float v = x * cs[d & 63] + xr * sn[d & 63];
            h[e] = f2bf(v);
        }
        *(ushort8*)&qh[base + c0] = h;
    }
}

// ---------------------------------------------------------------------------
// 5) extract V^T per head: vt[bh][d][t] = bf16(qkv[b,t, 4096 + h*128 + d])
// ---------------------------------------------------------------------------
__global__ __launch_bounds__(128) void k_vt(const unsigned short* __restrict__ qkvh,
                                            unsigned short* __restrict__ vt) {
    const int bh = blockIdx.x;    // 0..31
    const int tc = blockIdx.y;    // 0..31 (chunk of 64 t's)
    const int d = threadIdx.x;    // 0..127
    const int b = bh >> 4, h = bh & 15;
    unsigned short buf[64];
    const size_t src0 = ((size_t)(b * TT + tc * 64)) * QKVN + 4096 + h * 128 + d;
#pragma unroll
    for (int ttt = 0; ttt < 64; ttt++) buf[ttt] = qkvh[src0 + (size_t)ttt * QKVN];
    const size_t dst = ((size_t)bh * 128 + d) * TT + tc * 64;
#pragma unroll
    for (int i = 0; i < 8; i++)
        *(ushort8*)&vt[dst + i * 8] = *(const ushort8*)&buf[i * 8];
}

// ---------------------------------------------------------------------------
// 6) causal flash attention (unchanged: QBLK=64, KVBLK=64, dbuf staging,
//    XCD remap, heavy-qb-first).
// ---------------------------------------------------------------------------
__global__ __launch_bounds__(256) void k_flash(const unsigned short* __restrict__ qkvh,
                                               const unsigned short* __restrict__ vt,
                                               unsigned short* __restrict__ aoh,
                                               unsigned short* __restrict__ aol) {
    __shared__ unsigned short sK[2][64 * 128];
    __shared__ unsigned short sV[2][128 * 64];
    __shared__ unsigned short sP[4][16 * 64];

    const int L = blockIdx.y * gridDim.x + blockIdx.x;
    const int logical = (L & 7) * 128 + (L >> 3);
    const int bh = logical >> 5;
    const int qb = 31 - (logical & 31);
    const int b = bh >> 4, h = bh & 15;

    const int tid = threadIdx.x, wave = tid >> 6, lane = tid & 63;
    const int g = lane >> 4, r16 = lane & 15;
    const float scale = 0.08838834764831845f;   // 1/sqrt(128)

    bf16x8 qf[4];
    {
        const int qrow = qb * 64 + wave * 16 + r16;
        const size_t qbase = ((size_t)(b * TT) + qrow) * QKVN + h * 128;
#pragma unroll
        for (int kk = 0; kk < 4; kk++) {
            ushort8 u = *(const ushort8*)&qkvh[qbase + kk * 32 + g * 8];
            ushort8 o;
#pragma unroll
            for (int e = 0; e < 8; e++) o[e] = f2bf(bf2f(u[e]) * scale);
            qf[kk] = __builtin_bit_cast(bf16x8, o);
        }
    }

    f32x4 oacc[8];
#pragma unroll
    for (int n = 0; n < 8; n++) oacc[n] = (f32x4){0.f, 0.f, 0.f, 0.f};
    float mrun[4], lrun[4];
#pragma unroll
    for (int j = 0; j < 4; j++) { mrun[j] = -1e30f; lrun[j] = 0.f; }

    const int k_row_st = wave * 4 + (lane >> 4);    // + i*16 ; slot = lane&15
    const int v_row_st = wave * 8 + (lane >> 3);    // + i*32 ; slot = lane&7
    const int lidx = wave * 512 + lane * 8;

    auto stage = [&](int buf, int kb) {
#pragma unroll
        for (int i = 0; i < 4; i++) {
            int krow = i * 16 + k_row_st;
            int kcol = ((lane & 15) ^ (krow & 7)) << 3;
            GLOAD16(qkvh + ((size_t)(b * TT + kb * 64 + krow)) * QKVN + 2048 + h * 128 + kcol,
                    &sK[buf][i * 2048 + lidx]);
            int vrow = i * 32 + v_row_st;
            int vcol = ((lane & 7) ^ (vrow & 7)) << 3;
            GLOAD16(vt + ((size_t)bh * 128 + vrow) * TT + kb * 64 + vcol,
                    &sV[buf][i * 2048 + lidx]);
        }
    };

    const int nkb = qb + 1;
    int cur = 0;
    stage(0, 0);

    for (int kb = 0; kb < nkb; kb++) {
        __syncthreads();
        if (kb + 1 < nkb) stage(cur ^ 1, kb + 1);

        f32x4 sacc[4];
#pragma unroll
        for (int n = 0; n < 4; n++) sacc[n] = (f32x4){0.f, 0.f, 0.f, 0.f};
#pragma unroll
        for (int n = 0; n < 4; n++) {
            const int krow = n * 16 + r16;
            const int rbase = krow * 128;
            const int sw = krow & 7;
#pragma unroll
            for (int kk = 0; kk < 4; kk++) {
                int slot = (kk * 4 + g) ^ sw;
                bf16x8 kf = __builtin_bit_cast(bf16x8, *(const ushort8*)&sK[cur][rbase + slot * 8]);
                sacc[n] = __builtin_amdgcn_mfma_f32_16x16x32_bf16(qf[kk], kf, sacc[n], 0, 0, 0);
            }
        }

        const int key0 = kb * 64;
#pragma unroll
        for (int j = 0; j < 4; j++) {
            const int prow = g * 4 + j;
            const int qg = qb * 64 + wave * 16 + prow;
            float s0 = sacc[0][j], s1 = sacc[1][j], s2 = sacc[2][j], s3 = sacc[3][j];
            if (kb == qb) {
                if (key0 + r16 > qg)      s0 = -1e30f;
                if (key0 + 16 + r16 > qg) s1 = -1e30f;
                if (key0 + 32 + r16 > qg) s2 = -1e30f;
                if (key0 + 48 + r16 > qg) s3 = -1e30f;
            }
            float tmax = fmaxf(fmaxf(s0, s1), fmaxf(s2, s3));
#pragma unroll
            for (int off = 8; off >= 1; off >>= 1) tmax = fmaxf(tmax, __shfl_xor(tmax, off));
            float mnew = fmaxf(mrun[j], tmax);
            float corr = __expf(mrun[j] - mnew);
            float p0 = __expf(s0 - mnew), p1 = __expf(s1 - mnew);
            float p2 = __expf(s2 - mnew), p3 = __expf(s3 - mnew);
            float rs = (p0 + p1) + (p2 + p3);
#pragma unroll
            for (int off = 8; off >= 1; off >>= 1) rs += __shfl_xor(rs, off);
            lrun[j] = lrun[j] * corr + rs;
            mrun[j] = mnew;
#pragma unroll
            for (int n = 0; n < 8; n++) oacc[n][j] *= corr;
            const int pb = prow * 64, sw = prow & 7, e = r16 & 7, hi2 = (r16 >> 3);
            sP[wave][pb + (((0 + hi2) ^ sw) << 3) + e] = f2bf(p0);
            sP[wave][pb + (((2 + hi2) ^ sw) << 3) + e] = f2bf(p1);
            sP[wave][pb + (((4 + hi2) ^ sw) << 3) + e] = f2bf(p2);
            sP[wave][pb + (((6 + hi2) ^ sw) << 3) + e] = f2bf(p3);
        }

#pragma unroll
        for (int kk = 0; kk < 2; kk++) {
            const int slot = (kk * 4 + g) ^ (r16 & 7);
            bf16x8 pf = __builtin_bit_cast(bf16x8, *(const ushort8*)&sP[wave][r16 * 64 + slot * 8]);
#pragma unroll
            for (int n = 0; n < 8; n++) {
                const int d = n * 16 + r16;
                bf16x8 vf = __builtin_bit_cast(bf16x8, *(const ushort8*)&sV[cur][d * 64 + slot * 8]);
                oacc[n] = __builtin_amdgcn_mfma_f32_16x16x32_bf16(pf, vf, oacc[n], 0, 0, 0);
            }
        }
        cur ^= 1;
    }

#pragma unroll
    for (int j = 0; j < 4; j++) {
        float inv = 1.0f / lrun[j];
        int qg = qb * 64 + wave * 16 + g * 4 + j;
        size_t obase = ((size_t)(b * TT) + qg) * DM + h * 128;
#pragma unroll
        for (int n = 0; n < 8; n++) {
            float v = oacc[n][j] * inv;
            unsigned short hh = f2bf(v);
            aoh[obase + n * 16 + r16] = hh;
            aol[obase + n * 16 + r16] = f2bf(v - bf2f(hh));
        }
    }
}

// ---------------------------------------------------------------------------
extern "C" void kernel_launch(void* const* d_in, const int* in_sizes, int n_in,
                              void* d_out, int out_size, void* d_ws, size_t ws_size,
                              hipStream_t stream) {
    const float* x = (const float*)d_in[0];
    const float* Wqkv = (const float*)d_in[1];
    const float* Wproj = (const float*)d_in[2];
    const float* bproj = (const float*)d_in[3];
    // d_in[4] = mask (causal structure implemented directly)

    uint8_t* w = (uint8_t*)d_ws;
    auto alloc = [&](size_t bytes) { uint8_t* p = w; w += bytes; return p; };
    unsigned short* xh   = (unsigned short*)alloc(8388608ull * 2);   // x hi
    unsigned short* xl   = (unsigned short*)alloc(8388608ull * 2);   // x lo
    unsigned short* wqh  = (unsigned short*)alloc(12582912ull * 2);  // WqkvT hi [6144][2048]
    unsigned short* wph  = (unsigned short*)alloc(4194304ull * 2);   // WprojT hi [2048][2048]
    unsigned short* qkvh = (unsigned short*)alloc(25165824ull * 2);  // qkv hi [4096][6144]
    unsigned short* vtp  = (unsigned short*)alloc(8388608ull * 2);   // V^T [32][128][2048]
    unsigned short* aoh  = (unsigned short*)alloc(8388608ull * 2);   // attn out hi [4096][2048]
    unsigned short* aol  = (unsigned short*)alloc(8388608ull * 2);

    k_split<<<dim3(8192), dim3(256), 0, stream>>>(x, xh, xl, 2097152);
    k_tsplit<<<dim3(192, 64), dim3(32, 8), 0, stream>>>(Wqkv, wqh, 2048, 6144);
    k_tsplit<<<dim3(64, 64), dim3(32, 8), 0, stream>>>(Wproj, wph, 2048, 2048);
    k_gemm<0><<<dim3(48, 16), dim3(512), 0, stream>>>(xh, xl, wqh,
                                                      qkvh, nullptr, nullptr,
                                                      4096, 6144, 2048);
    k_rope<<<dim3(4096), dim3(256), 0, stream>>>(qkvh);
    k_vt<<<dim3(32, 32), dim3(128), 0, stream>>>(qkvh, vtp);
    k_flash<<<dim3(32, 32), dim3(256), 0, stream>>>(qkvh, vtp, aoh, aol);
    k_gemm<1><<<dim3(16, 16), dim3(512), 0, stream>>>(aoh, aol, wph,
                                                      nullptr, (float*)d_out, bproj,
                                                      4096, 2048, 2048);
}